// Round 3
// baseline (336.622 us; speedup 1.0000x reference)
//
#include <hip/hip_runtime.h>
#include <math.h>

#define DCOL 8192
#define PNUM 1024
#define BATCH 256
#define HISTLEN 101
#define WIN 10
#define NK 5
#define EPSF 1e-6f
#define SLICES 4
#define SLICE_COLS (DCOL/SLICES)        // 2048

// ws layout (float offsets)
#define WS_RECENT 0                     // 10*8192
#define WS_RINV   (WIN*DCOL)            // 81920, 5*8192
#define WS_PSTR   (WS_RINV + NK*DCOL)   // 122880, SLICES*1024
#define WS_PART   131072                // split-K partials, spl*256*1024

// ---------------------------------------------------------------------------
// K0: build `recent` (last 10 history rows with row hist_idx replaced by
// input_spikes[0]) and rinv[k][d] = 1/(sqrt(sum_w K2[k][w]*recent^2)+eps)
// ---------------------------------------------------------------------------
__global__ __launch_bounds__(256) void k0_prep(
    const float* __restrict__ spikes, const float* __restrict__ hist,
    const float* __restrict__ ck, const int* __restrict__ hidxp,
    float* __restrict__ ws)
{
  const int g = blockIdx.x * 256 + threadIdx.x;   // 0..2047
  const int col = g * 4;
  int hidx = hidxp[0] % HISTLEN;
  if (hidx < 0) hidx += HISTLEN;

  float k2[NK][WIN];
#pragma unroll
  for (int k = 0; k < NK; ++k)
#pragma unroll
    for (int w = 0; w < WIN; ++w) { float v = ck[k*WIN + w]; k2[k][w] = v * v; }

  float rn[NK][4];
#pragma unroll
  for (int k = 0; k < NK; ++k)
#pragma unroll
    for (int j = 0; j < 4; ++j) rn[k][j] = 0.f;

#pragma unroll
  for (int w = 0; w < WIN; ++w) {
    const int row = HISTLEN - WIN + w;            // 91..100
    const float* src = (row == hidx) ? spikes : (hist + (size_t)row * DCOL);
    const float4 r = *(const float4*)(src + col);
    *(float4*)(ws + WS_RECENT + w*DCOL + col) = r;
    const float rr[4] = { r.x, r.y, r.z, r.w };
#pragma unroll
    for (int k = 0; k < NK; ++k)
#pragma unroll
      for (int j = 0; j < 4; ++j) rn[k][j] += k2[k][w] * rr[j] * rr[j];
  }

#pragma unroll
  for (int k = 0; k < NK; ++k) {
    float o[4];
#pragma unroll
    for (int j = 0; j < 4; ++j) o[j] = 1.0f / (sqrtf(rn[k][j]) + EPSF);
    float4 v; v.x = o[0]; v.y = o[1]; v.z = o[2]; v.w = o[3];
    *(float4*)(ws + WS_RINV + k*DCOL + col) = v;
  }
}

// ---------------------------------------------------------------------------
// K1: per-(pattern, column-slice) strength partial.
// rt/t2 formulation: load chunk once, precompute r*t and t*t, then loop k
// sequentially with only 8 live accumulators; k2 coeffs from LDS.
// grid = (PNUM, SLICES). VGPR ~107 -> 16 waves/CU.
// ---------------------------------------------------------------------------
__global__ __launch_bounds__(256, 4) void k1_strength(
    const float* __restrict__ templ, const float* __restrict__ ck,
    const float* __restrict__ recent, const float* __restrict__ rinv,
    float* __restrict__ pstr)
{
  __shared__ float sk2[NK*WIN];
  __shared__ float red[4];
  const int p   = blockIdx.x;
  const int sl  = blockIdx.y;
  const int tid = threadIdx.x;
  if (tid < NK*WIN) { const float v = ck[tid]; sk2[tid] = v * v; }
  __syncthreads();

  const float* __restrict__ tbase = templ + (size_t)p * WIN * DCOL;
  float acc[4] = {0.f, 0.f, 0.f, 0.f};

#pragma unroll
  for (int c = 0; c < SLICE_COLS/1024; ++c) {     // 2 chunks of 1024 cols
    const int col = sl*SLICE_COLS + c*1024 + tid*4;
    float rt[WIN][4], t2[WIN][4];
#pragma unroll
    for (int w = 0; w < WIN; ++w) {
      const float4 t4 = *(const float4*)(tbase + w*DCOL + col);
      const float4 r4 = *(const float4*)(recent + w*DCOL + col);
      const float tt[4] = { t4.x, t4.y, t4.z, t4.w };
      const float rr[4] = { r4.x, r4.y, r4.z, r4.w };
#pragma unroll
      for (int j = 0; j < 4; ++j) {
        rt[w][j] = rr[j] * tt[j];
        t2[w][j] = tt[j] * tt[j];
      }
    }
#pragma unroll
    for (int k = 0; k < NK; ++k) {
      float nj[4] = {0.f,0.f,0.f,0.f}, tj[4] = {0.f,0.f,0.f,0.f};
#pragma unroll
      for (int w = 0; w < WIN; ++w) {
        const float cf = sk2[k*WIN + w];
#pragma unroll
        for (int j = 0; j < 4; ++j) {
          nj[j] = fmaf(cf, rt[w][j], nj[j]);
          tj[j] = fmaf(cf, t2[w][j], tj[j]);
        }
      }
      const float4 ri4 = *(const float4*)(rinv + k*DCOL + col);
      const float ri[4] = { ri4.x, ri4.y, ri4.z, ri4.w };
#pragma unroll
      for (int j = 0; j < 4; ++j)
        acc[j] += __fdividef(nj[j] * ri[j], sqrtf(tj[j]) + EPSF);
    }
  }

  float a = acc[0] + acc[1] + acc[2] + acc[3];
#pragma unroll
  for (int off = 32; off > 0; off >>= 1) a += __shfl_down(a, off, 64);
  if ((tid & 63) == 0) red[tid >> 6] = a;
  __syncthreads();
  if (tid == 0)
    pstr[sl*PNUM + p] = (red[0]+red[1]+red[2]+red[3]) * (1.0f / (NK * DCOL));
}

// ---------------------------------------------------------------------------
// K2: fp32 split-K GEMM, 128x128 tile, 8x8/thread, BK=16, 2-phase pipeline
// (next tile's global loads issued before the FMA phase). grid=(spl,8,2).
// ---------------------------------------------------------------------------
__global__ __launch_bounds__(256, 4) void k2_gemm(
    const float* __restrict__ A, const float* __restrict__ Wt,
    float* __restrict__ part, const int ksub)
{
  __shared__ float As[16][132];
  __shared__ float Ws[16][132];
  const int sk = blockIdx.x;
  const int bn = blockIdx.y;
  const int bm = blockIdx.z;
  const int tid = threadIdx.x;
  const int tx = tid & 15, ty = tid >> 4;
  const int srow = tid >> 2;                      // 0..63
  const int skg  = tid & 3;
  const size_t k0 = (size_t)sk * ksub;

  const float* Ap = A  + (size_t)(bm*128 + srow) * DCOL + k0 + skg*4;
  const float* Wp = Wt + (size_t)(bn*128 + srow) * DCOL + k0 + skg*4;

  float c[8][8];
#pragma unroll
  for (int i = 0; i < 8; ++i)
#pragma unroll
    for (int j = 0; j < 8; ++j) c[i][j] = 0.f;

  float4 a0 = *(const float4*)(Ap);
  float4 a1 = *(const float4*)(Ap + (size_t)64*DCOL);
  float4 w0 = *(const float4*)(Wp);
  float4 w1 = *(const float4*)(Wp + (size_t)64*DCOL);

  for (int kt = 0; kt < ksub; kt += 16) {
    __syncthreads();
    {
      const float av0[4] = {a0.x,a0.y,a0.z,a0.w};
      const float av1[4] = {a1.x,a1.y,a1.z,a1.w};
      const float wv0[4] = {w0.x,w0.y,w0.z,w0.w};
      const float wv1[4] = {w1.x,w1.y,w1.z,w1.w};
#pragma unroll
      for (int j = 0; j < 4; ++j) {
        As[skg*4+j][srow]    = av0[j];
        As[skg*4+j][srow+64] = av1[j];
        Ws[skg*4+j][srow]    = wv0[j];
        Ws[skg*4+j][srow+64] = wv1[j];
      }
    }
    __syncthreads();
    if (kt + 16 < ksub) {                         // prefetch next tile
      a0 = *(const float4*)(Ap + kt + 16);
      a1 = *(const float4*)(Ap + (size_t)64*DCOL + kt + 16);
      w0 = *(const float4*)(Wp + kt + 16);
      w1 = *(const float4*)(Wp + (size_t)64*DCOL + kt + 16);
    }
#pragma unroll
    for (int k = 0; k < 16; ++k) {
      const float4 x0 = *(const float4*)(&As[k][4*ty]);
      const float4 x1 = *(const float4*)(&As[k][64 + 4*ty]);
      const float4 y0 = *(const float4*)(&Ws[k][4*tx]);
      const float4 y1 = *(const float4*)(&Ws[k][64 + 4*tx]);
      const float a[8] = {x0.x,x0.y,x0.z,x0.w, x1.x,x1.y,x1.z,x1.w};
      const float w[8] = {y0.x,y0.y,y0.z,y0.w, y1.x,y1.y,y1.z,y1.w};
#pragma unroll
      for (int i = 0; i < 8; ++i)
#pragma unroll
        for (int j = 0; j < 8; ++j) c[i][j] = fmaf(a[i], w[j], c[i][j]);
    }
  }

  float* pp = part + (size_t)sk * (BATCH * PNUM);
#pragma unroll
  for (int i = 0; i < 8; ++i) {
    const int row = bm*128 + ((i < 4) ? (4*ty + i) : (64 + 4*ty + (i-4)));
    float4 lo, hi;
    lo.x=c[i][0]; lo.y=c[i][1]; lo.z=c[i][2]; lo.w=c[i][3];
    hi.x=c[i][4]; hi.y=c[i][5]; hi.z=c[i][6]; hi.w=c[i][7];
    *(float4*)(pp + (size_t)row*PNUM + bn*128 + 4*tx)      = lo;
    *(float4*)(pp + (size_t)row*PNUM + bn*128 + 64 + 4*tx) = hi;
  }
}

// ---------------------------------------------------------------------------
// K3: out[b][p] = sigmoid(sum_sl pstr[sl][p] + sum_s partial[s][b][p])
// ---------------------------------------------------------------------------
__global__ __launch_bounds__(256) void k3_combine(
    const float* __restrict__ part, const float* __restrict__ pstr,
    float* __restrict__ out, const int spl)
{
  const int g = blockIdx.x * 256 + threadIdx.x;
  const int i4 = g * 4;
  const int p = i4 & (PNUM - 1);
  float acc[4] = {0.f, 0.f, 0.f, 0.f};
#pragma unroll
  for (int sl = 0; sl < SLICES; ++sl) {
    const float4 s4 = *(const float4*)(pstr + sl*PNUM + p);
    acc[0]+=s4.x; acc[1]+=s4.y; acc[2]+=s4.z; acc[3]+=s4.w;
  }
  for (int s = 0; s < spl; ++s) {
    const float4 v = *(const float4*)(part + (size_t)s * (BATCH*PNUM) + i4);
    acc[0]+=v.x; acc[1]+=v.y; acc[2]+=v.z; acc[3]+=v.w;
  }
  float4 o;
  o.x = 1.f / (1.f + __expf(-acc[0]));
  o.y = 1.f / (1.f + __expf(-acc[1]));
  o.z = 1.f / (1.f + __expf(-acc[2]));
  o.w = 1.f / (1.f + __expf(-acc[3]));
  *(float4*)(out + i4) = o;
}

extern "C" void kernel_launch(void* const* d_in, const int* in_sizes, int n_in,
                              void* d_out, int out_size, void* d_ws, size_t ws_size,
                              hipStream_t stream)
{
  const float* spikes = (const float*)d_in[0];   // (256, 8192)
  const float* hist   = (const float*)d_in[1];   // (101, 8192)
  const float* templ  = (const float*)d_in[2];   // (1024, 10, 8192)
  const float* wts    = (const float*)d_in[3];   // (1024, 8192)
  const float* ck     = (const float*)d_in[4];   // (5, 10)
  const int*   hidx   = (const int*)d_in[5];     // scalar
  float* ws  = (float*)d_ws;
  float* out = (float*)d_out;

  int spl = 32;                                   // split-K factor
  while (spl > 1 &&
         ws_size < ((size_t)WS_PART + (size_t)spl * BATCH * PNUM) * 4)
    spl >>= 1;
  const int ksub = DCOL / spl;

  k0_prep<<<dim3(8), dim3(256), 0, stream>>>(spikes, hist, ck, hidx, ws);
  k1_strength<<<dim3(PNUM, SLICES), dim3(256), 0, stream>>>(
      templ, ck, ws + WS_RECENT, ws + WS_RINV, ws + WS_PSTR);
  k2_gemm<<<dim3(spl, PNUM/128, BATCH/128), dim3(256), 0, stream>>>(
      spikes, wts, ws + WS_PART, ksub);
  k3_combine<<<dim3(BATCH*PNUM/(256*4)), dim3(256), 0, stream>>>(
      ws + WS_PART, ws + WS_PSTR, out, spl);
}

// Round 4
// 205.281 us; speedup vs baseline: 1.6398x; 1.6398x over previous
//
#include <hip/hip_runtime.h>
#include <math.h>

#define DCOL 8192
#define PNUM 1024
#define BATCH 256
#define HISTLEN 101
#define WIN 10
#define NK 5
#define EPSF 1e-6f
#define SLICES 4
#define SLICE_COLS (DCOL/SLICES)        // 2048

// ws layout (float offsets)
#define WS_RECENT 0                     // 10*8192
#define WS_RINV   (WIN*DCOL)            // 81920, 5*8192
#define WS_PSTR   (WS_RINV + NK*DCOL)   // 122880, SLICES*1024
#define WS_K2     (WS_PSTR + SLICES*PNUM) // 126976, 50 floats (k^2 table)
#define WS_PART   131072                // split-K partials, spl*256*1024

// ---------------------------------------------------------------------------
// K0: build `recent` (last 10 history rows with row hist_idx replaced by
// input_spikes[0]), rinv[k][d] = 1/(sqrt(sum_w K2[k][w]*recent^2)+eps),
// and the squared-kernel table k2 -> ws (for k1's scalar loads).
// ---------------------------------------------------------------------------
__global__ __launch_bounds__(256) void k0_prep(
    const float* __restrict__ spikes, const float* __restrict__ hist,
    const float* __restrict__ ck, const int* __restrict__ hidxp,
    float* __restrict__ ws)
{
  const int g = blockIdx.x * 256 + threadIdx.x;   // 0..2047
  const int col = g * 4;
  int hidx = hidxp[0] % HISTLEN;
  if (hidx < 0) hidx += HISTLEN;

  if (blockIdx.x == 0 && threadIdx.x < NK*WIN) {
    const float v = ck[threadIdx.x];
    ws[WS_K2 + threadIdx.x] = v * v;
  }

  float k2[NK][WIN];
#pragma unroll
  for (int k = 0; k < NK; ++k)
#pragma unroll
    for (int w = 0; w < WIN; ++w) { float v = ck[k*WIN + w]; k2[k][w] = v * v; }

  float rn[NK][4];
#pragma unroll
  for (int k = 0; k < NK; ++k)
#pragma unroll
    for (int j = 0; j < 4; ++j) rn[k][j] = 0.f;

#pragma unroll
  for (int w = 0; w < WIN; ++w) {
    const int row = HISTLEN - WIN + w;            // 91..100
    const float* src = (row == hidx) ? spikes : (hist + (size_t)row * DCOL);
    const float4 r = *(const float4*)(src + col);
    *(float4*)(ws + WS_RECENT + w*DCOL + col) = r;
    const float rr[4] = { r.x, r.y, r.z, r.w };
#pragma unroll
    for (int k = 0; k < NK; ++k)
#pragma unroll
      for (int j = 0; j < 4; ++j) rn[k][j] += k2[k][w] * rr[j] * rr[j];
  }

#pragma unroll
  for (int k = 0; k < NK; ++k) {
    float o[4];
#pragma unroll
    for (int j = 0; j < 4; ++j) o[j] = 1.0f / (sqrtf(rn[k][j]) + EPSF);
    float4 v; v.x = o[0]; v.y = o[1]; v.z = o[2]; v.w = o[3];
    *(float4*)(ws + WS_RINV + k*DCOL + col) = v;
  }
}

// ---------------------------------------------------------------------------
// K1: per-(pattern, column-slice) strength partial.
// Persistent state = nj[5][4]+tj[5][4] accumulators only (40 VGPR).
// Coefficients come from ws via wave-uniform s_load (SGPR, no VGPR cost).
// No big live arrays -> no spill; unrolled w-loop pipelines global loads.
// ---------------------------------------------------------------------------
__global__ __launch_bounds__(256) void k1_strength(
    const float* __restrict__ templ, const float* __restrict__ wk2,
    const float* __restrict__ recent, const float* __restrict__ rinv,
    float* __restrict__ pstr)
{
  __shared__ float red[4];
  const int p   = blockIdx.x;
  const int sl  = blockIdx.y;
  const int tid = threadIdx.x;

  const float* __restrict__ tbase  = templ + (size_t)p * WIN * DCOL + sl*SLICE_COLS;
  const float* __restrict__ rbase  = recent + sl*SLICE_COLS;
  const float* __restrict__ ribase = rinv   + sl*SLICE_COLS;

  float acc[4] = {0.f, 0.f, 0.f, 0.f};

#pragma unroll
  for (int c = 0; c < SLICE_COLS/1024; ++c) {     // 2 chunks of 1024 cols
    const int col = c*1024 + tid*4;
    float nj[NK][4], tj[NK][4];
#pragma unroll
    for (int k = 0; k < NK; ++k)
#pragma unroll
      for (int j = 0; j < 4; ++j) { nj[k][j] = 0.f; tj[k][j] = 0.f; }

#pragma unroll
    for (int w = 0; w < WIN; ++w) {
      const float4 t4 = *(const float4*)(tbase + w*DCOL + col);
      const float4 r4 = *(const float4*)(rbase + w*DCOL + col);
      const float x[4] = { r4.x*t4.x, r4.y*t4.y, r4.z*t4.z, r4.w*t4.w };
      const float y[4] = { t4.x*t4.x, t4.y*t4.y, t4.z*t4.z, t4.w*t4.w };
#pragma unroll
      for (int k = 0; k < NK; ++k) {
        const float cf = wk2[k*WIN + w];          // uniform -> SGPR
#pragma unroll
        for (int j = 0; j < 4; ++j) {
          nj[k][j] = fmaf(cf, x[j], nj[k][j]);
          tj[k][j] = fmaf(cf, y[j], tj[k][j]);
        }
      }
    }

#pragma unroll
    for (int k = 0; k < NK; ++k) {
      const float4 ri4 = *(const float4*)(ribase + k*DCOL + col);
      const float ri[4] = { ri4.x, ri4.y, ri4.z, ri4.w };
#pragma unroll
      for (int j = 0; j < 4; ++j)
        acc[j] += nj[k][j] * ri[j] * rsqrtf(tj[k][j]);
    }
  }

  float a = acc[0] + acc[1] + acc[2] + acc[3];
#pragma unroll
  for (int off = 32; off > 0; off >>= 1) a += __shfl_down(a, off, 64);
  if ((tid & 63) == 0) red[tid >> 6] = a;
  __syncthreads();
  if (tid == 0)
    pstr[sl*PNUM + p] = (red[0]+red[1]+red[2]+red[3]) * (1.0f / (NK * DCOL));
}

// ---------------------------------------------------------------------------
// K2: fp32 split-K GEMM, 128x128 tile, 8x8/thread, BK=16, 2-phase pipeline.
// ---------------------------------------------------------------------------
__global__ __launch_bounds__(256, 4) void k2_gemm(
    const float* __restrict__ A, const float* __restrict__ Wt,
    float* __restrict__ part, const int ksub)
{
  __shared__ float As[16][132];
  __shared__ float Ws[16][132];
  const int sk = blockIdx.x;
  const int bn = blockIdx.y;
  const int bm = blockIdx.z;
  const int tid = threadIdx.x;
  const int tx = tid & 15, ty = tid >> 4;
  const int srow = tid >> 2;                      // 0..63
  const int skg  = tid & 3;
  const size_t k0 = (size_t)sk * ksub;

  const float* Ap = A  + (size_t)(bm*128 + srow) * DCOL + k0 + skg*4;
  const float* Wp = Wt + (size_t)(bn*128 + srow) * DCOL + k0 + skg*4;

  float c[8][8];
#pragma unroll
  for (int i = 0; i < 8; ++i)
#pragma unroll
    for (int j = 0; j < 8; ++j) c[i][j] = 0.f;

  float4 a0 = *(const float4*)(Ap);
  float4 a1 = *(const float4*)(Ap + (size_t)64*DCOL);
  float4 w0 = *(const float4*)(Wp);
  float4 w1 = *(const float4*)(Wp + (size_t)64*DCOL);

  for (int kt = 0; kt < ksub; kt += 16) {
    __syncthreads();
    {
      const float av0[4] = {a0.x,a0.y,a0.z,a0.w};
      const float av1[4] = {a1.x,a1.y,a1.z,a1.w};
      const float wv0[4] = {w0.x,w0.y,w0.z,w0.w};
      const float wv1[4] = {w1.x,w1.y,w1.z,w1.w};
#pragma unroll
      for (int j = 0; j < 4; ++j) {
        As[skg*4+j][srow]    = av0[j];
        As[skg*4+j][srow+64] = av1[j];
        Ws[skg*4+j][srow]    = wv0[j];
        Ws[skg*4+j][srow+64] = wv1[j];
      }
    }
    __syncthreads();
    if (kt + 16 < ksub) {                         // prefetch next tile
      a0 = *(const float4*)(Ap + kt + 16);
      a1 = *(const float4*)(Ap + (size_t)64*DCOL + kt + 16);
      w0 = *(const float4*)(Wp + kt + 16);
      w1 = *(const float4*)(Wp + (size_t)64*DCOL + kt + 16);
    }
#pragma unroll
    for (int k = 0; k < 16; ++k) {
      const float4 x0 = *(const float4*)(&As[k][4*ty]);
      const float4 x1 = *(const float4*)(&As[k][64 + 4*ty]);
      const float4 y0 = *(const float4*)(&Ws[k][4*tx]);
      const float4 y1 = *(const float4*)(&Ws[k][64 + 4*tx]);
      const float a[8] = {x0.x,x0.y,x0.z,x0.w, x1.x,x1.y,x1.z,x1.w};
      const float w[8] = {y0.x,y0.y,y0.z,y0.w, y1.x,y1.y,y1.z,y1.w};
#pragma unroll
      for (int i = 0; i < 8; ++i)
#pragma unroll
        for (int j = 0; j < 8; ++j) c[i][j] = fmaf(a[i], w[j], c[i][j]);
    }
  }

  float* pp = part + (size_t)sk * (BATCH * PNUM);
#pragma unroll
  for (int i = 0; i < 8; ++i) {
    const int row = bm*128 + ((i < 4) ? (4*ty + i) : (64 + 4*ty + (i-4)));
    float4 lo, hi;
    lo.x=c[i][0]; lo.y=c[i][1]; lo.z=c[i][2]; lo.w=c[i][3];
    hi.x=c[i][4]; hi.y=c[i][5]; hi.z=c[i][6]; hi.w=c[i][7];
    *(float4*)(pp + (size_t)row*PNUM + bn*128 + 4*tx)      = lo;
    *(float4*)(pp + (size_t)row*PNUM + bn*128 + 64 + 4*tx) = hi;
  }
}

// ---------------------------------------------------------------------------
// K3: out[b][p] = sigmoid(sum_sl pstr[sl][p] + sum_s partial[s][b][p])
// ---------------------------------------------------------------------------
__global__ __launch_bounds__(256) void k3_combine(
    const float* __restrict__ part, const float* __restrict__ pstr,
    float* __restrict__ out, const int spl)
{
  const int g = blockIdx.x * 256 + threadIdx.x;
  const int i4 = g * 4;
  const int p = i4 & (PNUM - 1);
  float acc[4] = {0.f, 0.f, 0.f, 0.f};
#pragma unroll
  for (int sl = 0; sl < SLICES; ++sl) {
    const float4 s4 = *(const float4*)(pstr + sl*PNUM + p);
    acc[0]+=s4.x; acc[1]+=s4.y; acc[2]+=s4.z; acc[3]+=s4.w;
  }
  for (int s = 0; s < spl; ++s) {
    const float4 v = *(const float4*)(part + (size_t)s * (BATCH*PNUM) + i4);
    acc[0]+=v.x; acc[1]+=v.y; acc[2]+=v.z; acc[3]+=v.w;
  }
  float4 o;
  o.x = 1.f / (1.f + __expf(-acc[0]));
  o.y = 1.f / (1.f + __expf(-acc[1]));
  o.z = 1.f / (1.f + __expf(-acc[2]));
  o.w = 1.f / (1.f + __expf(-acc[3]));
  *(float4*)(out + i4) = o;
}

extern "C" void kernel_launch(void* const* d_in, const int* in_sizes, int n_in,
                              void* d_out, int out_size, void* d_ws, size_t ws_size,
                              hipStream_t stream)
{
  const float* spikes = (const float*)d_in[0];   // (256, 8192)
  const float* hist   = (const float*)d_in[1];   // (101, 8192)
  const float* templ  = (const float*)d_in[2];   // (1024, 10, 8192)
  const float* wts    = (const float*)d_in[3];   // (1024, 8192)
  const float* ck     = (const float*)d_in[4];   // (5, 10)
  const int*   hidx   = (const int*)d_in[5];     // scalar
  float* ws  = (float*)d_ws;
  float* out = (float*)d_out;

  int spl = 32;                                   // split-K factor
  while (spl > 1 &&
         ws_size < ((size_t)WS_PART + (size_t)spl * BATCH * PNUM) * 4)
    spl >>= 1;
  const int ksub = DCOL / spl;

  k0_prep<<<dim3(8), dim3(256), 0, stream>>>(spikes, hist, ck, hidx, ws);
  k1_strength<<<dim3(PNUM, SLICES), dim3(256), 0, stream>>>(
      templ, ws + WS_K2, ws + WS_RECENT, ws + WS_RINV, ws + WS_PSTR);
  k2_gemm<<<dim3(spl, PNUM/128, BATCH/128), dim3(256), 0, stream>>>(
      spikes, wts, ws + WS_PART, ksub);
  k3_combine<<<dim3(BATCH*PNUM/(256*4)), dim3(256), 0, stream>>>(
      ws + WS_PART, ws + WS_PSTR, out, spl);
}

// Round 5
// 174.193 us; speedup vs baseline: 1.9325x; 1.1785x over previous
//
#include <hip/hip_runtime.h>
#include <math.h>

#define DCOL 8192
#define PNUM 1024
#define BATCH 256
#define HISTLEN 101
#define WIN 10
#define NK 5
#define EPSF 1e-6f
#define SLICES 4
#define SLICE_COLS (DCOL/SLICES)        // 2048

// ws layout (float offsets)
#define WS_RECENT 0                     // 10*8192
#define WS_RINV   (WIN*DCOL)            // 81920, 5*8192
#define WS_PSTR   (WS_RINV + NK*DCOL)   // 122880, SLICES*1024
#define WS_K2     (WS_PSTR + SLICES*PNUM) // 126976, 50 floats (k^2 table)
#define WS_PART   131072                // split-K partials, spl*256*1024

// ---------------------------------------------------------------------------
// K0: build `recent` (last 10 history rows with row hist_idx replaced by
// input_spikes[0]), rinv[k][d] = 1/(sqrt(sum_w K2[k][w]*recent^2)+eps),
// and the squared-kernel table k2 -> ws (for k1's scalar loads).
// ---------------------------------------------------------------------------
__global__ __launch_bounds__(256) void k0_prep(
    const float* __restrict__ spikes, const float* __restrict__ hist,
    const float* __restrict__ ck, const int* __restrict__ hidxp,
    float* __restrict__ ws)
{
  const int g = blockIdx.x * 256 + threadIdx.x;   // 0..2047
  const int col = g * 4;
  int hidx = hidxp[0] % HISTLEN;
  if (hidx < 0) hidx += HISTLEN;

  if (blockIdx.x == 0 && threadIdx.x < NK*WIN) {
    const float v = ck[threadIdx.x];
    ws[WS_K2 + threadIdx.x] = v * v;
  }

  float k2[NK][WIN];
#pragma unroll
  for (int k = 0; k < NK; ++k)
#pragma unroll
    for (int w = 0; w < WIN; ++w) { float v = ck[k*WIN + w]; k2[k][w] = v * v; }

  float rn[NK][4];
#pragma unroll
  for (int k = 0; k < NK; ++k)
#pragma unroll
    for (int j = 0; j < 4; ++j) rn[k][j] = 0.f;

#pragma unroll
  for (int w = 0; w < WIN; ++w) {
    const int row = HISTLEN - WIN + w;            // 91..100
    const float* src = (row == hidx) ? spikes : (hist + (size_t)row * DCOL);
    const float4 r = *(const float4*)(src + col);
    *(float4*)(ws + WS_RECENT + w*DCOL + col) = r;
    const float rr[4] = { r.x, r.y, r.z, r.w };
#pragma unroll
    for (int k = 0; k < NK; ++k)
#pragma unroll
      for (int j = 0; j < 4; ++j) rn[k][j] += k2[k][w] * rr[j] * rr[j];
  }

#pragma unroll
  for (int k = 0; k < NK; ++k) {
    float o[4];
#pragma unroll
    for (int j = 0; j < 4; ++j) o[j] = 1.0f / (sqrtf(rn[k][j]) + EPSF);
    float4 v; v.x = o[0]; v.y = o[1]; v.z = o[2]; v.w = o[3];
    *(float4*)(ws + WS_RINV + k*DCOL + col) = v;
  }
}

// ---------------------------------------------------------------------------
// K1: per-(pattern, column-slice) strength partial.
// Template loads (the only HBM-miss stream) go through an explicit 6-deep
// register prefetch ring spanning the chunk boundary: each load issues ~6
// iterations (~600 cyc of VALU) before its use -> ~6 KB in flight per wave,
// HBM-streaming-bound. recent/rinv are L2-resident, read on demand.
// All ring indices are compile-time constants (full unroll) -> registers.
// ---------------------------------------------------------------------------
__global__ __launch_bounds__(256) void k1_strength(
    const float* __restrict__ templ, const float* __restrict__ wk2,
    const float* __restrict__ recent, const float* __restrict__ rinv,
    float* __restrict__ pstr)
{
  __shared__ float red[4];
  const int p   = blockIdx.x;
  const int sl  = blockIdx.y;
  const int tid = threadIdx.x;

  const float* __restrict__ tbase  = templ + (size_t)p * WIN * DCOL + sl*SLICE_COLS;
  const float* __restrict__ rbase  = recent + sl*SLICE_COLS;
  const float* __restrict__ ribase = rinv   + sl*SLICE_COLS;

  const int col0 = tid * 4;              // chunk 0 columns
  const int col1 = 1024 + tid * 4;       // chunk 1 columns

  float4 tp[6];
  tp[0] = *(const float4*)(tbase + 0*DCOL + col0);
  tp[1] = *(const float4*)(tbase + 1*DCOL + col0);
  tp[2] = *(const float4*)(tbase + 2*DCOL + col0);
  tp[3] = *(const float4*)(tbase + 3*DCOL + col0);
  tp[4] = *(const float4*)(tbase + 4*DCOL + col0);
  tp[5] = *(const float4*)(tbase + 5*DCOL + col0);

  float acc[4] = {0.f, 0.f, 0.f, 0.f};

  // ---------------- chunk 0 ----------------
  {
    float nj[NK][4], tj[NK][4];
#pragma unroll
    for (int k = 0; k < NK; ++k)
#pragma unroll
      for (int j = 0; j < 4; ++j) { nj[k][j] = 0.f; tj[k][j] = 0.f; }

#pragma unroll
    for (int w = 0; w < WIN; ++w) {
      const float4 t4 = tp[w % 6];
      // refill the slot with the load 6 steps ahead (crosses into chunk 1)
      if (w + 6 < WIN)
        tp[w % 6] = *(const float4*)(tbase + (w + 6)*DCOL + col0);
      else
        tp[w % 6] = *(const float4*)(tbase + (w - 4)*DCOL + col1);
      const float4 r4 = *(const float4*)(rbase + w*DCOL + col0);
      const float x[4] = { r4.x*t4.x, r4.y*t4.y, r4.z*t4.z, r4.w*t4.w };
      const float y[4] = { t4.x*t4.x, t4.y*t4.y, t4.z*t4.z, t4.w*t4.w };
#pragma unroll
      for (int k = 0; k < NK; ++k) {
        const float cf = wk2[k*WIN + w];          // uniform -> SGPR
#pragma unroll
        for (int j = 0; j < 4; ++j) {
          nj[k][j] = fmaf(cf, x[j], nj[k][j]);
          tj[k][j] = fmaf(cf, y[j], tj[k][j]);
        }
      }
    }
#pragma unroll
    for (int k = 0; k < NK; ++k) {
      const float4 ri4 = *(const float4*)(ribase + k*DCOL + col0);
      const float ri[4] = { ri4.x, ri4.y, ri4.z, ri4.w };
#pragma unroll
      for (int j = 0; j < 4; ++j)
        acc[j] += nj[k][j] * ri[j] * rsqrtf(tj[k][j]);
    }
  }

  // ---------------- chunk 1 ----------------
  {
    float nj[NK][4], tj[NK][4];
#pragma unroll
    for (int k = 0; k < NK; ++k)
#pragma unroll
      for (int j = 0; j < 4; ++j) { nj[k][j] = 0.f; tj[k][j] = 0.f; }

#pragma unroll
    for (int w = 0; w < WIN; ++w) {
      const float4 t4 = tp[(w + 4) % 6];          // continuation of the ring
      if (w + 6 < WIN)
        tp[(w + 4) % 6] = *(const float4*)(tbase + (w + 6)*DCOL + col1);
      const float4 r4 = *(const float4*)(rbase + w*DCOL + col1);
      const float x[4] = { r4.x*t4.x, r4.y*t4.y, r4.z*t4.z, r4.w*t4.w };
      const float y[4] = { t4.x*t4.x, t4.y*t4.y, t4.z*t4.z, t4.w*t4.w };
#pragma unroll
      for (int k = 0; k < NK; ++k) {
        const float cf = wk2[k*WIN + w];
#pragma unroll
        for (int j = 0; j < 4; ++j) {
          nj[k][j] = fmaf(cf, x[j], nj[k][j]);
          tj[k][j] = fmaf(cf, y[j], tj[k][j]);
        }
      }
    }
#pragma unroll
    for (int k = 0; k < NK; ++k) {
      const float4 ri4 = *(const float4*)(ribase + k*DCOL + col1);
      const float ri[4] = { ri4.x, ri4.y, ri4.z, ri4.w };
#pragma unroll
      for (int j = 0; j < 4; ++j)
        acc[j] += nj[k][j] * ri[j] * rsqrtf(tj[k][j]);
    }
  }

  float a = acc[0] + acc[1] + acc[2] + acc[3];
#pragma unroll
  for (int off = 32; off > 0; off >>= 1) a += __shfl_down(a, off, 64);
  if ((tid & 63) == 0) red[tid >> 6] = a;
  __syncthreads();
  if (tid == 0)
    pstr[sl*PNUM + p] = (red[0]+red[1]+red[2]+red[3]) * (1.0f / (NK * DCOL));
}

// ---------------------------------------------------------------------------
// K2: fp32 split-K GEMM, 128x128 tile, 8x8/thread, BK=16, 2-phase pipeline.
// ---------------------------------------------------------------------------
__global__ __launch_bounds__(256, 4) void k2_gemm(
    const float* __restrict__ A, const float* __restrict__ Wt,
    float* __restrict__ part, const int ksub)
{
  __shared__ float As[16][132];
  __shared__ float Ws[16][132];
  const int sk = blockIdx.x;
  const int bn = blockIdx.y;
  const int bm = blockIdx.z;
  const int tid = threadIdx.x;
  const int tx = tid & 15, ty = tid >> 4;
  const int srow = tid >> 2;                      // 0..63
  const int skg  = tid & 3;
  const size_t k0 = (size_t)sk * ksub;

  const float* Ap = A  + (size_t)(bm*128 + srow) * DCOL + k0 + skg*4;
  const float* Wp = Wt + (size_t)(bn*128 + srow) * DCOL + k0 + skg*4;

  float c[8][8];
#pragma unroll
  for (int i = 0; i < 8; ++i)
#pragma unroll
    for (int j = 0; j < 8; ++j) c[i][j] = 0.f;

  float4 a0 = *(const float4*)(Ap);
  float4 a1 = *(const float4*)(Ap + (size_t)64*DCOL);
  float4 w0 = *(const float4*)(Wp);
  float4 w1 = *(const float4*)(Wp + (size_t)64*DCOL);

  for (int kt = 0; kt < ksub; kt += 16) {
    __syncthreads();
    {
      const float av0[4] = {a0.x,a0.y,a0.z,a0.w};
      const float av1[4] = {a1.x,a1.y,a1.z,a1.w};
      const float wv0[4] = {w0.x,w0.y,w0.z,w0.w};
      const float wv1[4] = {w1.x,w1.y,w1.z,w1.w};
#pragma unroll
      for (int j = 0; j < 4; ++j) {
        As[skg*4+j][srow]    = av0[j];
        As[skg*4+j][srow+64] = av1[j];
        Ws[skg*4+j][srow]    = wv0[j];
        Ws[skg*4+j][srow+64] = wv1[j];
      }
    }
    __syncthreads();
    if (kt + 16 < ksub) {                         // prefetch next tile
      a0 = *(const float4*)(Ap + kt + 16);
      a1 = *(const float4*)(Ap + (size_t)64*DCOL + kt + 16);
      w0 = *(const float4*)(Wp + kt + 16);
      w1 = *(const float4*)(Wp + (size_t)64*DCOL + kt + 16);
    }
#pragma unroll
    for (int k = 0; k < 16; ++k) {
      const float4 x0 = *(const float4*)(&As[k][4*ty]);
      const float4 x1 = *(const float4*)(&As[k][64 + 4*ty]);
      const float4 y0 = *(const float4*)(&Ws[k][4*tx]);
      const float4 y1 = *(const float4*)(&Ws[k][64 + 4*tx]);
      const float a[8] = {x0.x,x0.y,x0.z,x0.w, x1.x,x1.y,x1.z,x1.w};
      const float w[8] = {y0.x,y0.y,y0.z,y0.w, y1.x,y1.y,y1.z,y1.w};
#pragma unroll
      for (int i = 0; i < 8; ++i)
#pragma unroll
        for (int j = 0; j < 8; ++j) c[i][j] = fmaf(a[i], w[j], c[i][j]);
    }
  }

  float* pp = part + (size_t)sk * (BATCH * PNUM);
#pragma unroll
  for (int i = 0; i < 8; ++i) {
    const int row = bm*128 + ((i < 4) ? (4*ty + i) : (64 + 4*ty + (i-4)));
    float4 lo, hi;
    lo.x=c[i][0]; lo.y=c[i][1]; lo.z=c[i][2]; lo.w=c[i][3];
    hi.x=c[i][4]; hi.y=c[i][5]; hi.z=c[i][6]; hi.w=c[i][7];
    *(float4*)(pp + (size_t)row*PNUM + bn*128 + 4*tx)      = lo;
    *(float4*)(pp + (size_t)row*PNUM + bn*128 + 64 + 4*tx) = hi;
  }
}

// ---------------------------------------------------------------------------
// K3: out[b][p] = sigmoid(sum_sl pstr[sl][p] + sum_s partial[s][b][p])
// ---------------------------------------------------------------------------
__global__ __launch_bounds__(256) void k3_combine(
    const float* __restrict__ part, const float* __restrict__ pstr,
    float* __restrict__ out, const int spl)
{
  const int g = blockIdx.x * 256 + threadIdx.x;
  const int i4 = g * 4;
  const int p = i4 & (PNUM - 1);
  float acc[4] = {0.f, 0.f, 0.f, 0.f};
#pragma unroll
  for (int sl = 0; sl < SLICES; ++sl) {
    const float4 s4 = *(const float4*)(pstr + sl*PNUM + p);
    acc[0]+=s4.x; acc[1]+=s4.y; acc[2]+=s4.z; acc[3]+=s4.w;
  }
  for (int s = 0; s < spl; ++s) {
    const float4 v = *(const float4*)(part + (size_t)s * (BATCH*PNUM) + i4);
    acc[0]+=v.x; acc[1]+=v.y; acc[2]+=v.z; acc[3]+=v.w;
  }
  float4 o;
  o.x = 1.f / (1.f + __expf(-acc[0]));
  o.y = 1.f / (1.f + __expf(-acc[1]));
  o.z = 1.f / (1.f + __expf(-acc[2]));
  o.w = 1.f / (1.f + __expf(-acc[3]));
  *(float4*)(out + i4) = o;
}

extern "C" void kernel_launch(void* const* d_in, const int* in_sizes, int n_in,
                              void* d_out, int out_size, void* d_ws, size_t ws_size,
                              hipStream_t stream)
{
  const float* spikes = (const float*)d_in[0];   // (256, 8192)
  const float* hist   = (const float*)d_in[1];   // (101, 8192)
  const float* templ  = (const float*)d_in[2];   // (1024, 10, 8192)
  const float* wts    = (const float*)d_in[3];   // (1024, 8192)
  const float* ck     = (const float*)d_in[4];   // (5, 10)
  const int*   hidx   = (const int*)d_in[5];     // scalar
  float* ws  = (float*)d_ws;
  float* out = (float*)d_out;

  int spl = 32;                                   // split-K factor
  while (spl > 1 &&
         ws_size < ((size_t)WS_PART + (size_t)spl * BATCH * PNUM) * 4)
    spl >>= 1;
  const int ksub = DCOL / spl;

  k0_prep<<<dim3(8), dim3(256), 0, stream>>>(spikes, hist, ck, hidx, ws);
  k1_strength<<<dim3(PNUM, SLICES), dim3(256), 0, stream>>>(
      templ, ws + WS_K2, ws + WS_RECENT, ws + WS_RINV, ws + WS_PSTR);
  k2_gemm<<<dim3(spl, PNUM/128, BATCH/128), dim3(256), 0, stream>>>(
      spikes, wts, ws + WS_PART, ksub);
  k3_combine<<<dim3(BATCH*PNUM/(256*4)), dim3(256), 0, stream>>>(
      ws + WS_PART, ws + WS_PSTR, out, spl);
}

// Round 6
// 169.175 us; speedup vs baseline: 1.9898x; 1.0297x over previous
//
#include <hip/hip_runtime.h>
#include <math.h>

#define DCOL 8192
#define PNUM 1024
#define BATCH 256
#define HISTLEN 101
#define WIN 10
#define NK 5
#define EPSF 1e-6f
#define SLICES 8
#define SLICE_COLS (DCOL/SLICES)        // 1024

// ws layout (float offsets)
#define WS_RECENT 0                         // 10*8192            -> 81920
#define WS_RINV   (WIN*DCOL)                // 81920, 5*8192      -> 122880
#define WS_PSTR   (WS_RINV + NK*DCOL)       // 122880, 8*1024     -> 131072
#define WS_K2     (WS_PSTR + SLICES*PNUM)   // 131072, 50 floats
#define WS_PART   131584                    // split-K partials, spl*256*1024

// ---------------------------------------------------------------------------
// K0: build `recent` (last 10 history rows with row hist_idx replaced by
// input_spikes[0]), rinv[k][d] = 1/(sqrt(sum_w K2[k][w]*recent^2)+eps),
// and the squared-kernel table k2 -> ws (for k1's scalar loads).
// ---------------------------------------------------------------------------
__global__ __launch_bounds__(256) void k0_prep(
    const float* __restrict__ spikes, const float* __restrict__ hist,
    const float* __restrict__ ck, const int* __restrict__ hidxp,
    float* __restrict__ ws)
{
  const int g = blockIdx.x * 256 + threadIdx.x;   // 0..2047
  const int col = g * 4;
  int hidx = hidxp[0] % HISTLEN;
  if (hidx < 0) hidx += HISTLEN;

  if (blockIdx.x == 0 && threadIdx.x < NK*WIN) {
    const float v = ck[threadIdx.x];
    ws[WS_K2 + threadIdx.x] = v * v;
  }

  float k2[NK][WIN];
#pragma unroll
  for (int k = 0; k < NK; ++k)
#pragma unroll
    for (int w = 0; w < WIN; ++w) { float v = ck[k*WIN + w]; k2[k][w] = v * v; }

  float rn[NK][4];
#pragma unroll
  for (int k = 0; k < NK; ++k)
#pragma unroll
    for (int j = 0; j < 4; ++j) rn[k][j] = 0.f;

#pragma unroll
  for (int w = 0; w < WIN; ++w) {
    const int row = HISTLEN - WIN + w;            // 91..100
    const float* src = (row == hidx) ? spikes : (hist + (size_t)row * DCOL);
    const float4 r = *(const float4*)(src + col);
    *(float4*)(ws + WS_RECENT + w*DCOL + col) = r;
    const float rr[4] = { r.x, r.y, r.z, r.w };
#pragma unroll
    for (int k = 0; k < NK; ++k)
#pragma unroll
      for (int j = 0; j < 4; ++j) rn[k][j] += k2[k][w] * rr[j] * rr[j];
  }

#pragma unroll
  for (int k = 0; k < NK; ++k) {
    float o[4];
#pragma unroll
    for (int j = 0; j < 4; ++j) o[j] = 1.0f / (sqrtf(rn[k][j]) + EPSF);
    float4 v; v.x = o[0]; v.y = o[1]; v.z = o[2]; v.w = o[3];
    *(float4*)(ws + WS_RINV + k*DCOL + col) = v;
  }
}

// ---------------------------------------------------------------------------
// K1: per-(pattern, 1024-col slice) strength partial.  grid = (1024, 8).
// The template stream is the ONLY vmem traffic in the w-loop:
//  - all 10 `recent` rows preloaded to registers (L2-resident; issued before
//    any template use, so in-order vmcnt completion makes their waits free)
//  - templates go through a 6-deep register ring -> counted vmcnt waits keep
//    ~5 outstanding 1KB loads per wave (~40KB/CU in flight at 8 waves/CU)
//  - rinv loads deferred to the epilogue (ring drained there anyway)
// Live state ~120 VGPR; plain launch_bounds (no min-waves hint: round-3
// showed the hint makes the allocator pin 64 VGPR and spill to scratch).
// ---------------------------------------------------------------------------
__global__ __launch_bounds__(256) void k1_strength(
    const float* __restrict__ templ, const float* __restrict__ wk2,
    const float* __restrict__ recent, const float* __restrict__ rinv,
    float* __restrict__ pstr)
{
  __shared__ float red[4];
  const int p   = blockIdx.x;
  const int sl  = blockIdx.y;
  const int tid = threadIdx.x;
  const int col = tid * 4;

  const float* __restrict__ tbase  = templ + (size_t)p * WIN * DCOL + sl*SLICE_COLS;
  const float* __restrict__ rbase  = recent + sl*SLICE_COLS;
  const float* __restrict__ ribase = rinv   + sl*SLICE_COLS;

  // preload recent rows (issued first; in-order completion => free waits)
  float4 r[WIN];
#pragma unroll
  for (int w = 0; w < WIN; ++w)
    r[w] = *(const float4*)(rbase + w*DCOL + col);

  // 6-deep template prefetch ring (the only HBM-miss stream)
  float4 tp[6];
#pragma unroll
  for (int i = 0; i < 6; ++i)
    tp[i] = *(const float4*)(tbase + i*DCOL + col);

  float nj[NK][4], tj[NK][4];
#pragma unroll
  for (int k = 0; k < NK; ++k)
#pragma unroll
    for (int j = 0; j < 4; ++j) { nj[k][j] = 0.f; tj[k][j] = 0.f; }

#pragma unroll
  for (int w = 0; w < WIN; ++w) {
    const float4 t4 = tp[w % 6];
    if (w + 6 < WIN)                               // refill 6 ahead
      tp[w % 6] = *(const float4*)(tbase + (w + 6)*DCOL + col);
    const float4 r4 = r[w];
    const float x[4] = { r4.x*t4.x, r4.y*t4.y, r4.z*t4.z, r4.w*t4.w };
    const float y[4] = { t4.x*t4.x, t4.y*t4.y, t4.z*t4.z, t4.w*t4.w };
#pragma unroll
    for (int k = 0; k < NK; ++k) {
      const float cf = wk2[k*WIN + w];             // uniform -> s_load
#pragma unroll
      for (int j = 0; j < 4; ++j) {
        nj[k][j] = fmaf(cf, x[j], nj[k][j]);
        tj[k][j] = fmaf(cf, y[j], tj[k][j]);
      }
    }
  }

  float acc[4] = {0.f, 0.f, 0.f, 0.f};
#pragma unroll
  for (int k = 0; k < NK; ++k) {
    const float4 ri4 = *(const float4*)(ribase + k*DCOL + col);
    const float ri[4] = { ri4.x, ri4.y, ri4.z, ri4.w };
#pragma unroll
    for (int j = 0; j < 4; ++j)
      acc[j] += nj[k][j] * ri[j] * rsqrtf(tj[k][j]);
  }

  float a = acc[0] + acc[1] + acc[2] + acc[3];
#pragma unroll
  for (int off = 32; off > 0; off >>= 1) a += __shfl_down(a, off, 64);
  if ((tid & 63) == 0) red[tid >> 6] = a;
  __syncthreads();
  if (tid == 0)
    pstr[sl*PNUM + p] = (red[0]+red[1]+red[2]+red[3]) * (1.0f / (NK * DCOL));
}

// ---------------------------------------------------------------------------
// K2: fp32 split-K GEMM, 128x128 tile, 8x8/thread, BK=16, 2-phase pipeline.
// ---------------------------------------------------------------------------
__global__ __launch_bounds__(256, 4) void k2_gemm(
    const float* __restrict__ A, const float* __restrict__ Wt,
    float* __restrict__ part, const int ksub)
{
  __shared__ float As[16][132];
  __shared__ float Ws[16][132];
  const int sk = blockIdx.x;
  const int bn = blockIdx.y;
  const int bm = blockIdx.z;
  const int tid = threadIdx.x;
  const int tx = tid & 15, ty = tid >> 4;
  const int srow = tid >> 2;                      // 0..63
  const int skg  = tid & 3;
  const size_t k0 = (size_t)sk * ksub;

  const float* Ap = A  + (size_t)(bm*128 + srow) * DCOL + k0 + skg*4;
  const float* Wp = Wt + (size_t)(bn*128 + srow) * DCOL + k0 + skg*4;

  float c[8][8];
#pragma unroll
  for (int i = 0; i < 8; ++i)
#pragma unroll
    for (int j = 0; j < 8; ++j) c[i][j] = 0.f;

  float4 a0 = *(const float4*)(Ap);
  float4 a1 = *(const float4*)(Ap + (size_t)64*DCOL);
  float4 w0 = *(const float4*)(Wp);
  float4 w1 = *(const float4*)(Wp + (size_t)64*DCOL);

  for (int kt = 0; kt < ksub; kt += 16) {
    __syncthreads();
    {
      const float av0[4] = {a0.x,a0.y,a0.z,a0.w};
      const float av1[4] = {a1.x,a1.y,a1.z,a1.w};
      const float wv0[4] = {w0.x,w0.y,w0.z,w0.w};
      const float wv1[4] = {w1.x,w1.y,w1.z,w1.w};
#pragma unroll
      for (int j = 0; j < 4; ++j) {
        As[skg*4+j][srow]    = av0[j];
        As[skg*4+j][srow+64] = av1[j];
        Ws[skg*4+j][srow]    = wv0[j];
        Ws[skg*4+j][srow+64] = wv1[j];
      }
    }
    __syncthreads();
    if (kt + 16 < ksub) {                         // prefetch next tile
      a0 = *(const float4*)(Ap + kt + 16);
      a1 = *(const float4*)(Ap + (size_t)64*DCOL + kt + 16);
      w0 = *(const float4*)(Wp + kt + 16);
      w1 = *(const float4*)(Wp + (size_t)64*DCOL + kt + 16);
    }
#pragma unroll
    for (int k = 0; k < 16; ++k) {
      const float4 x0 = *(const float4*)(&As[k][4*ty]);
      const float4 x1 = *(const float4*)(&As[k][64 + 4*ty]);
      const float4 y0 = *(const float4*)(&Ws[k][4*tx]);
      const float4 y1 = *(const float4*)(&Ws[k][64 + 4*tx]);
      const float a[8] = {x0.x,x0.y,x0.z,x0.w, x1.x,x1.y,x1.z,x1.w};
      const float w[8] = {y0.x,y0.y,y0.z,y0.w, y1.x,y1.y,y1.z,y1.w};
#pragma unroll
      for (int i = 0; i < 8; ++i)
#pragma unroll
        for (int j = 0; j < 8; ++j) c[i][j] = fmaf(a[i], w[j], c[i][j]);
    }
  }

  float* pp = part + (size_t)sk * (BATCH * PNUM);
#pragma unroll
  for (int i = 0; i < 8; ++i) {
    const int row = bm*128 + ((i < 4) ? (4*ty + i) : (64 + 4*ty + (i-4)));
    float4 lo, hi;
    lo.x=c[i][0]; lo.y=c[i][1]; lo.z=c[i][2]; lo.w=c[i][3];
    hi.x=c[i][4]; hi.y=c[i][5]; hi.z=c[i][6]; hi.w=c[i][7];
    *(float4*)(pp + (size_t)row*PNUM + bn*128 + 4*tx)      = lo;
    *(float4*)(pp + (size_t)row*PNUM + bn*128 + 64 + 4*tx) = hi;
  }
}

// ---------------------------------------------------------------------------
// K3: out[b][p] = sigmoid(sum_sl pstr[sl][p] + sum_s partial[s][b][p])
// ---------------------------------------------------------------------------
__global__ __launch_bounds__(256) void k3_combine(
    const float* __restrict__ part, const float* __restrict__ pstr,
    float* __restrict__ out, const int spl)
{
  const int g = blockIdx.x * 256 + threadIdx.x;
  const int i4 = g * 4;
  const int p = i4 & (PNUM - 1);
  float acc[4] = {0.f, 0.f, 0.f, 0.f};
#pragma unroll
  for (int sl = 0; sl < SLICES; ++sl) {
    const float4 s4 = *(const float4*)(pstr + sl*PNUM + p);
    acc[0]+=s4.x; acc[1]+=s4.y; acc[2]+=s4.z; acc[3]+=s4.w;
  }
  for (int s = 0; s < spl; ++s) {
    const float4 v = *(const float4*)(part + (size_t)s * (BATCH*PNUM) + i4);
    acc[0]+=v.x; acc[1]+=v.y; acc[2]+=v.z; acc[3]+=v.w;
  }
  float4 o;
  o.x = 1.f / (1.f + __expf(-acc[0]));
  o.y = 1.f / (1.f + __expf(-acc[1]));
  o.z = 1.f / (1.f + __expf(-acc[2]));
  o.w = 1.f / (1.f + __expf(-acc[3]));
  *(float4*)(out + i4) = o;
}

extern "C" void kernel_launch(void* const* d_in, const int* in_sizes, int n_in,
                              void* d_out, int out_size, void* d_ws, size_t ws_size,
                              hipStream_t stream)
{
  const float* spikes = (const float*)d_in[0];   // (256, 8192)
  const float* hist   = (const float*)d_in[1];   // (101, 8192)
  const float* templ  = (const float*)d_in[2];   // (1024, 10, 8192)
  const float* wts    = (const float*)d_in[3];   // (1024, 8192)
  const float* ck     = (const float*)d_in[4];   // (5, 10)
  const int*   hidx   = (const int*)d_in[5];     // scalar
  float* ws  = (float*)d_ws;
  float* out = (float*)d_out;

  int spl = 32;                                   // split-K factor
  while (spl > 1 &&
         ws_size < ((size_t)WS_PART + (size_t)spl * BATCH * PNUM) * 4)
    spl >>= 1;
  const int ksub = DCOL / spl;

  k0_prep<<<dim3(8), dim3(256), 0, stream>>>(spikes, hist, ck, hidx, ws);
  k1_strength<<<dim3(PNUM, SLICES), dim3(256), 0, stream>>>(
      templ, ws + WS_K2, ws + WS_RECENT, ws + WS_RINV, ws + WS_PSTR);
  k2_gemm<<<dim3(spl, PNUM/128, BATCH/128), dim3(256), 0, stream>>>(
      spikes, wts, ws + WS_PART, ksub);
  k3_combine<<<dim3(BATCH*PNUM/(256*4)), dim3(256), 0, stream>>>(
      ws + WS_PART, ws + WS_PSTR, out, spl);
}

// Round 7
// 165.289 us; speedup vs baseline: 2.0366x; 1.0235x over previous
//
#include <hip/hip_runtime.h>
#include <math.h>

#define DCOL 8192
#define PNUM 1024
#define BATCH 256
#define HISTLEN 101
#define WIN 10
#define NK 5
#define EPSF 1e-6f
#define SLICES 8
#define SLICE_COLS (DCOL/SLICES)        // 1024

// ws layout (float offsets)
#define WS_RECENT 0                         // 10*8192            -> 81920
#define WS_RINV   (WIN*DCOL)                // 81920, 5*8192      -> 122880
#define WS_PSTR   (WS_RINV + NK*DCOL)       // 122880, 8*1024     -> 131072
#define WS_K2     (WS_PSTR + SLICES*PNUM)   // 131072, 50 floats
#define WS_PART   131584                    // split-K partials, spl*256*1024

// ---------------------------------------------------------------------------
// K0: build `recent` (last 10 history rows with row hist_idx replaced by
// input_spikes[0]), rinv[k][d] = 1/(sqrt(sum_w K2[k][w]*recent^2)+eps),
// and the squared-kernel table k2 -> ws (for k1's scalar loads).
// ---------------------------------------------------------------------------
__global__ __launch_bounds__(256) void k0_prep(
    const float* __restrict__ spikes, const float* __restrict__ hist,
    const float* __restrict__ ck, const int* __restrict__ hidxp,
    float* __restrict__ ws)
{
  const int g = blockIdx.x * 256 + threadIdx.x;   // 0..2047
  const int col = g * 4;
  int hidx = hidxp[0] % HISTLEN;
  if (hidx < 0) hidx += HISTLEN;

  if (blockIdx.x == 0 && threadIdx.x < NK*WIN) {
    const float v = ck[threadIdx.x];
    ws[WS_K2 + threadIdx.x] = v * v;
  }

  float k2[NK][WIN];
#pragma unroll
  for (int k = 0; k < NK; ++k)
#pragma unroll
    for (int w = 0; w < WIN; ++w) { float v = ck[k*WIN + w]; k2[k][w] = v * v; }

  float rn[NK][4];
#pragma unroll
  for (int k = 0; k < NK; ++k)
#pragma unroll
    for (int j = 0; j < 4; ++j) rn[k][j] = 0.f;

#pragma unroll
  for (int w = 0; w < WIN; ++w) {
    const int row = HISTLEN - WIN + w;            // 91..100
    const float* src = (row == hidx) ? spikes : (hist + (size_t)row * DCOL);
    const float4 r = *(const float4*)(src + col);
    *(float4*)(ws + WS_RECENT + w*DCOL + col) = r;
    const float rr[4] = { r.x, r.y, r.z, r.w };
#pragma unroll
    for (int k = 0; k < NK; ++k)
#pragma unroll
      for (int j = 0; j < 4; ++j) rn[k][j] += k2[k][w] * rr[j] * rr[j];
  }

#pragma unroll
  for (int k = 0; k < NK; ++k) {
    float o[4];
#pragma unroll
    for (int j = 0; j < 4; ++j) o[j] = 1.0f / (sqrtf(rn[k][j]) + EPSF);
    float4 v; v.x = o[0]; v.y = o[1]; v.z = o[2]; v.w = o[3];
    *(float4*)(ws + WS_RINV + k*DCOL + col) = v;
  }
}

// ---------------------------------------------------------------------------
// K1: per-(pattern, 1024-col slice) strength partial.  grid = (8, 1024):
// x = slice (fastest), y = pattern. Co-resident blocks therefore cover a
// CONTIGUOUS sliding window of whole patterns (~20 MB) instead of 4 KB
// islands scattered over all 336 MB -- DRAM row-buffer friendly.
//  - all 10 `recent` rows preloaded to registers (L2-resident)
//  - templates via 6-deep register ring (counted vmcnt waits)
//  - rinv loads deferred to the epilogue
// ---------------------------------------------------------------------------
__global__ __launch_bounds__(256) void k1_strength(
    const float* __restrict__ templ, const float* __restrict__ wk2,
    const float* __restrict__ recent, const float* __restrict__ rinv,
    float* __restrict__ pstr)
{
  __shared__ float red[4];
  const int sl  = blockIdx.x;
  const int p   = blockIdx.y;
  const int tid = threadIdx.x;
  const int col = tid * 4;

  const float* __restrict__ tbase  = templ + (size_t)p * WIN * DCOL + sl*SLICE_COLS;
  const float* __restrict__ rbase  = recent + sl*SLICE_COLS;
  const float* __restrict__ ribase = rinv   + sl*SLICE_COLS;

  // preload recent rows (issued first; in-order completion => free waits)
  float4 r[WIN];
#pragma unroll
  for (int w = 0; w < WIN; ++w)
    r[w] = *(const float4*)(rbase + w*DCOL + col);

  // 6-deep template prefetch ring (the only HBM-miss stream)
  float4 tp[6];
#pragma unroll
  for (int i = 0; i < 6; ++i)
    tp[i] = *(const float4*)(tbase + i*DCOL + col);

  float nj[NK][4], tj[NK][4];
#pragma unroll
  for (int k = 0; k < NK; ++k)
#pragma unroll
    for (int j = 0; j < 4; ++j) { nj[k][j] = 0.f; tj[k][j] = 0.f; }

#pragma unroll
  for (int w = 0; w < WIN; ++w) {
    const float4 t4 = tp[w % 6];
    if (w + 6 < WIN)                               // refill 6 ahead
      tp[w % 6] = *(const float4*)(tbase + (w + 6)*DCOL + col);
    const float4 r4 = r[w];
    const float x[4] = { r4.x*t4.x, r4.y*t4.y, r4.z*t4.z, r4.w*t4.w };
    const float y[4] = { t4.x*t4.x, t4.y*t4.y, t4.z*t4.z, t4.w*t4.w };
#pragma unroll
    for (int k = 0; k < NK; ++k) {
      const float cf = wk2[k*WIN + w];             // uniform -> s_load
#pragma unroll
      for (int j = 0; j < 4; ++j) {
        nj[k][j] = fmaf(cf, x[j], nj[k][j]);
        tj[k][j] = fmaf(cf, y[j], tj[k][j]);
      }
    }
  }

  float acc[4] = {0.f, 0.f, 0.f, 0.f};
#pragma unroll
  for (int k = 0; k < NK; ++k) {
    const float4 ri4 = *(const float4*)(ribase + k*DCOL + col);
    const float ri[4] = { ri4.x, ri4.y, ri4.z, ri4.w };
#pragma unroll
    for (int j = 0; j < 4; ++j)
      acc[j] += nj[k][j] * ri[j] * rsqrtf(tj[k][j]);
  }

  float a = acc[0] + acc[1] + acc[2] + acc[3];
#pragma unroll
  for (int off = 32; off > 0; off >>= 1) a += __shfl_down(a, off, 64);
  if ((tid & 63) == 0) red[tid >> 6] = a;
  __syncthreads();
  if (tid == 0)
    pstr[sl*PNUM + p] = (red[0]+red[1]+red[2]+red[3]) * (1.0f / (NK * DCOL));
}

// ---------------------------------------------------------------------------
// K2: fp32 split-K GEMM, 128x128 tile, 8x8/thread, BK=16, 2-phase pipeline.
// ---------------------------------------------------------------------------
__global__ __launch_bounds__(256, 4) void k2_gemm(
    const float* __restrict__ A, const float* __restrict__ Wt,
    float* __restrict__ part, const int ksub)
{
  __shared__ float As[16][132];
  __shared__ float Ws[16][132];
  const int sk = blockIdx.x;
  const int bn = blockIdx.y;
  const int bm = blockIdx.z;
  const int tid = threadIdx.x;
  const int tx = tid & 15, ty = tid >> 4;
  const int srow = tid >> 2;                      // 0..63
  const int skg  = tid & 3;
  const size_t k0 = (size_t)sk * ksub;

  const float* Ap = A  + (size_t)(bm*128 + srow) * DCOL + k0 + skg*4;
  const float* Wp = Wt + (size_t)(bn*128 + srow) * DCOL + k0 + skg*4;

  float c[8][8];
#pragma unroll
  for (int i = 0; i < 8; ++i)
#pragma unroll
    for (int j = 0; j < 8; ++j) c[i][j] = 0.f;

  float4 a0 = *(const float4*)(Ap);
  float4 a1 = *(const float4*)(Ap + (size_t)64*DCOL);
  float4 w0 = *(const float4*)(Wp);
  float4 w1 = *(const float4*)(Wp + (size_t)64*DCOL);

  for (int kt = 0; kt < ksub; kt += 16) {
    __syncthreads();
    {
      const float av0[4] = {a0.x,a0.y,a0.z,a0.w};
      const float av1[4] = {a1.x,a1.y,a1.z,a1.w};
      const float wv0[4] = {w0.x,w0.y,w0.z,w0.w};
      const float wv1[4] = {w1.x,w1.y,w1.z,w1.w};
#pragma unroll
      for (int j = 0; j < 4; ++j) {
        As[skg*4+j][srow]    = av0[j];
        As[skg*4+j][srow+64] = av1[j];
        Ws[skg*4+j][srow]    = wv0[j];
        Ws[skg*4+j][srow+64] = wv1[j];
      }
    }
    __syncthreads();
    if (kt + 16 < ksub) {                         // prefetch next tile
      a0 = *(const float4*)(Ap + kt + 16);
      a1 = *(const float4*)(Ap + (size_t)64*DCOL + kt + 16);
      w0 = *(const float4*)(Wp + kt + 16);
      w1 = *(const float4*)(Wp + (size_t)64*DCOL + kt + 16);
    }
#pragma unroll
    for (int k = 0; k < 16; ++k) {
      const float4 x0 = *(const float4*)(&As[k][4*ty]);
      const float4 x1 = *(const float4*)(&As[k][64 + 4*ty]);
      const float4 y0 = *(const float4*)(&Ws[k][4*tx]);
      const float4 y1 = *(const float4*)(&Ws[k][64 + 4*tx]);
      const float a[8] = {x0.x,x0.y,x0.z,x0.w, x1.x,x1.y,x1.z,x1.w};
      const float w[8] = {y0.x,y0.y,y0.z,y0.w, y1.x,y1.y,y1.z,y1.w};
#pragma unroll
      for (int i = 0; i < 8; ++i)
#pragma unroll
        for (int j = 0; j < 8; ++j) c[i][j] = fmaf(a[i], w[j], c[i][j]);
    }
  }

  float* pp = part + (size_t)sk * (BATCH * PNUM);
#pragma unroll
  for (int i = 0; i < 8; ++i) {
    const int row = bm*128 + ((i < 4) ? (4*ty + i) : (64 + 4*ty + (i-4)));
    float4 lo, hi;
    lo.x=c[i][0]; lo.y=c[i][1]; lo.z=c[i][2]; lo.w=c[i][3];
    hi.x=c[i][4]; hi.y=c[i][5]; hi.z=c[i][6]; hi.w=c[i][7];
    *(float4*)(pp + (size_t)row*PNUM + bn*128 + 4*tx)      = lo;
    *(float4*)(pp + (size_t)row*PNUM + bn*128 + 64 + 4*tx) = hi;
  }
}

// ---------------------------------------------------------------------------
// K3: out[b][p] = sigmoid(sum_sl pstr[sl][p] + sum_s partial[s][b][p])
// ---------------------------------------------------------------------------
__global__ __launch_bounds__(256) void k3_combine(
    const float* __restrict__ part, const float* __restrict__ pstr,
    float* __restrict__ out, const int spl)
{
  const int g = blockIdx.x * 256 + threadIdx.x;
  const int i4 = g * 4;
  const int p = i4 & (PNUM - 1);
  float acc[4] = {0.f, 0.f, 0.f, 0.f};
#pragma unroll
  for (int sl = 0; sl < SLICES; ++sl) {
    const float4 s4 = *(const float4*)(pstr + sl*PNUM + p);
    acc[0]+=s4.x; acc[1]+=s4.y; acc[2]+=s4.z; acc[3]+=s4.w;
  }
  for (int s = 0; s < spl; ++s) {
    const float4 v = *(const float4*)(part + (size_t)s * (BATCH*PNUM) + i4);
    acc[0]+=v.x; acc[1]+=v.y; acc[2]+=v.z; acc[3]+=v.w;
  }
  float4 o;
  o.x = 1.f / (1.f + __expf(-acc[0]));
  o.y = 1.f / (1.f + __expf(-acc[1]));
  o.z = 1.f / (1.f + __expf(-acc[2]));
  o.w = 1.f / (1.f + __expf(-acc[3]));
  *(float4*)(out + i4) = o;
}

extern "C" void kernel_launch(void* const* d_in, const int* in_sizes, int n_in,
                              void* d_out, int out_size, void* d_ws, size_t ws_size,
                              hipStream_t stream)
{
  const float* spikes = (const float*)d_in[0];   // (256, 8192)
  const float* hist   = (const float*)d_in[1];   // (101, 8192)
  const float* templ  = (const float*)d_in[2];   // (1024, 10, 8192)
  const float* wts    = (const float*)d_in[3];   // (1024, 8192)
  const float* ck     = (const float*)d_in[4];   // (5, 10)
  const int*   hidx   = (const int*)d_in[5];     // scalar
  float* ws  = (float*)d_ws;
  float* out = (float*)d_out;

  int spl = 32;                                   // split-K factor
  while (spl > 1 &&
         ws_size < ((size_t)WS_PART + (size_t)spl * BATCH * PNUM) * 4)
    spl >>= 1;
  const int ksub = DCOL / spl;

  k0_prep<<<dim3(8), dim3(256), 0, stream>>>(spikes, hist, ck, hidx, ws);
  k1_strength<<<dim3(SLICES, PNUM), dim3(256), 0, stream>>>(
      templ, ws + WS_K2, ws + WS_RECENT, ws + WS_RINV, ws + WS_PSTR);
  k2_gemm<<<dim3(spl, PNUM/128, BATCH/128), dim3(256), 0, stream>>>(
      spikes, wts, ws + WS_PART, ksub);
  k3_combine<<<dim3(BATCH*PNUM/(256*4)), dim3(256), 0, stream>>>(
      ws + WS_PART, ws + WS_PSTR, out, spl);
}

// Round 8
// 105.330 us; speedup vs baseline: 3.1959x; 1.5692x over previous
//
#include <hip/hip_runtime.h>
#include <math.h>

#define DCOL 8192
#define PNUM 1024
#define BATCH 256
#define HISTLEN 101
#define WIN 10
#define NK 5
#define EPSF 1e-6f
#define SLICES 8
#define SLICE_COLS (DCOL/SLICES)        // 1024
#define BKK 32                          // k2 K-step

// ws layout (float offsets)
#define WS_RECENT 0                         // 10*8192            -> 81920
#define WS_RINV   (WIN*DCOL)                // 81920, 5*8192      -> 122880
#define WS_PSTR   (WS_RINV + NK*DCOL)       // 122880, 8*1024     -> 131072
#define WS_K2     (WS_PSTR + SLICES*PNUM)   // 131072, 50 floats
#define WS_PART   131584                    // split-K partials, spl*256*1024

typedef __attribute__((ext_vector_type(8))) short bf16x8;   // 8 bf16 = 4 VGPR
typedef __attribute__((ext_vector_type(4))) float f32x4;

__device__ inline short f2bf_s(float x) {               // RNE fp32->bf16 bits
  union { float f; unsigned u; } c; c.f = x;
  unsigned r = c.u + 0x7FFFu + ((c.u >> 16) & 1u);
  return (short)(r >> 16);
}
__device__ inline float bf2f_s(short b) {
  union { unsigned u; float f; } c; c.u = ((unsigned)(unsigned short)b) << 16;
  return c.f;
}

// ---------------------------------------------------------------------------
// K0: build `recent` (last 10 history rows with row hist_idx replaced by
// input_spikes[0]), rinv[k][d] = 1/(sqrt(sum_w K2[k][w]*recent^2)+eps),
// and the squared-kernel table k2 -> ws.
// ---------------------------------------------------------------------------
__global__ __launch_bounds__(256) void k0_prep(
    const float* __restrict__ spikes, const float* __restrict__ hist,
    const float* __restrict__ ck, const int* __restrict__ hidxp,
    float* __restrict__ ws)
{
  const int g = blockIdx.x * 256 + threadIdx.x;   // 0..2047
  const int col = g * 4;
  int hidx = hidxp[0] % HISTLEN;
  if (hidx < 0) hidx += HISTLEN;

  if (blockIdx.x == 0 && threadIdx.x < NK*WIN) {
    const float v = ck[threadIdx.x];
    ws[WS_K2 + threadIdx.x] = v * v;
  }

  float k2[NK][WIN];
#pragma unroll
  for (int k = 0; k < NK; ++k)
#pragma unroll
    for (int w = 0; w < WIN; ++w) { float v = ck[k*WIN + w]; k2[k][w] = v * v; }

  float rn[NK][4];
#pragma unroll
  for (int k = 0; k < NK; ++k)
#pragma unroll
    for (int j = 0; j < 4; ++j) rn[k][j] = 0.f;

#pragma unroll
  for (int w = 0; w < WIN; ++w) {
    const int row = HISTLEN - WIN + w;            // 91..100
    const float* src = (row == hidx) ? spikes : (hist + (size_t)row * DCOL);
    const float4 r = *(const float4*)(src + col);
    *(float4*)(ws + WS_RECENT + w*DCOL + col) = r;
    const float rr[4] = { r.x, r.y, r.z, r.w };
#pragma unroll
    for (int k = 0; k < NK; ++k)
#pragma unroll
      for (int j = 0; j < 4; ++j) rn[k][j] += k2[k][w] * rr[j] * rr[j];
  }

#pragma unroll
  for (int k = 0; k < NK; ++k) {
    float o[4];
#pragma unroll
    for (int j = 0; j < 4; ++j) o[j] = 1.0f / (sqrtf(rn[k][j]) + EPSF);
    float4 v; v.x = o[0]; v.y = o[1]; v.z = o[2]; v.w = o[3];
    *(float4*)(ws + WS_RINV + k*DCOL + col) = v;
  }
}

// ---------------------------------------------------------------------------
// K1: per-(pattern, 1024-col slice) strength partial. grid = (8, 1024).
// (unchanged from round 7)
// ---------------------------------------------------------------------------
__global__ __launch_bounds__(256) void k1_strength(
    const float* __restrict__ templ, const float* __restrict__ wk2,
    const float* __restrict__ recent, const float* __restrict__ rinv,
    float* __restrict__ pstr)
{
  __shared__ float red[4];
  const int sl  = blockIdx.x;
  const int p   = blockIdx.y;
  const int tid = threadIdx.x;
  const int col = tid * 4;

  const float* __restrict__ tbase  = templ + (size_t)p * WIN * DCOL + sl*SLICE_COLS;
  const float* __restrict__ rbase  = recent + sl*SLICE_COLS;
  const float* __restrict__ ribase = rinv   + sl*SLICE_COLS;

  float4 r[WIN];
#pragma unroll
  for (int w = 0; w < WIN; ++w)
    r[w] = *(const float4*)(rbase + w*DCOL + col);

  float4 tp[6];
#pragma unroll
  for (int i = 0; i < 6; ++i)
    tp[i] = *(const float4*)(tbase + i*DCOL + col);

  float nj[NK][4], tj[NK][4];
#pragma unroll
  for (int k = 0; k < NK; ++k)
#pragma unroll
    for (int j = 0; j < 4; ++j) { nj[k][j] = 0.f; tj[k][j] = 0.f; }

#pragma unroll
  for (int w = 0; w < WIN; ++w) {
    const float4 t4 = tp[w % 6];
    if (w + 6 < WIN)
      tp[w % 6] = *(const float4*)(tbase + (w + 6)*DCOL + col);
    const float4 r4 = r[w];
    const float x[4] = { r4.x*t4.x, r4.y*t4.y, r4.z*t4.z, r4.w*t4.w };
    const float y[4] = { t4.x*t4.x, t4.y*t4.y, t4.z*t4.z, t4.w*t4.w };
#pragma unroll
    for (int k = 0; k < NK; ++k) {
      const float cf = wk2[k*WIN + w];
#pragma unroll
      for (int j = 0; j < 4; ++j) {
        nj[k][j] = fmaf(cf, x[j], nj[k][j]);
        tj[k][j] = fmaf(cf, y[j], tj[k][j]);
      }
    }
  }

  float acc[4] = {0.f, 0.f, 0.f, 0.f};
#pragma unroll
  for (int k = 0; k < NK; ++k) {
    const float4 ri4 = *(const float4*)(ribase + k*DCOL + col);
    const float ri[4] = { ri4.x, ri4.y, ri4.z, ri4.w };
#pragma unroll
    for (int j = 0; j < 4; ++j)
      acc[j] += nj[k][j] * ri[j] * rsqrtf(tj[k][j]);
  }

  float a = acc[0] + acc[1] + acc[2] + acc[3];
#pragma unroll
  for (int off = 32; off > 0; off >>= 1) a += __shfl_down(a, off, 64);
  if ((tid & 63) == 0) red[tid >> 6] = a;
  __syncthreads();
  if (tid == 0)
    pstr[sl*PNUM + p] = (red[0]+red[1]+red[2]+red[3]) * (1.0f / (NK * DCOL));
}

// ---------------------------------------------------------------------------
// K2: split-bf16 MFMA GEMM. C = A_hi*W_hi + A_hi*W_lo + A_lo*W_hi (lo*lo
// dropped, ~2^-18 rel). BM=256 (whole batch; W read exactly once), BN=128,
// BK=32, 512 threads (8 waves, each 32 rows x 128 cols), spl split-K.
// grid = (spl, 8) = 256 blocks = exactly 1/CU at spl=32.
// LDS planes [kgrp][row][8] bf16 -> frag ds_read_b128 16B-aligned,
// conflict-free (lanes 0..15 stride 16B = all 32 banks).
// mfma_f32_16x16x32_bf16: A[m=lane&15][k=(lane>>4)*8+j],
// B[k=(lane>>4)*8+j][n=lane&15]; D: col=lane&15, row=(lane>>4)*4+reg (m89).
// ---------------------------------------------------------------------------
__global__ __launch_bounds__(512) void k2_mfma(
    const float* __restrict__ A, const float* __restrict__ Wt,
    float* __restrict__ part, const int ksub)
{
  __shared__ short Ah[4][256][8], Al[4][256][8];   // 16 KB each
  __shared__ short Wh[4][128][8], Wl[4][128][8];   // 8 KB each -> 48 KB total

  const int sk  = blockIdx.x;
  const int bn  = blockIdx.y;
  const int tid = threadIdx.x;          // 0..511
  const int lane = tid & 63;
  const int wid  = tid >> 6;            // 0..7
  const size_t k0 = (size_t)sk * ksub;

  // staging: 8 threads per row, 1 float4 (4 k) each; 64 rows per pass.
  const int srow = tid >> 3;            // 0..63
  const int skc  = (tid & 7) * 4;       // k offset 0..28
  const int skg  = skc >> 3;            // kgrp
  const int sko  = skc & 7;             // 0 or 4

  const float* Ap = A  + (size_t)srow * DCOL + k0 + skc;
  const float* Wp = Wt + (size_t)(bn*128 + srow) * DCOL + k0 + skc;

  f32x4 acc[2][8];
#pragma unroll
  for (int mt = 0; mt < 2; ++mt)
#pragma unroll
    for (int nt = 0; nt < 8; ++nt)
#pragma unroll
      for (int r = 0; r < 4; ++r) acc[mt][nt][r] = 0.f;

  const int niter = ksub / BKK;
  float4 ra[4], rw[2];
#pragma unroll
  for (int p = 0; p < 4; ++p) ra[p] = *(const float4*)(Ap + (size_t)(p*64)*DCOL);
#pragma unroll
  for (int p = 0; p < 2; ++p) rw[p] = *(const float4*)(Wp + (size_t)(p*64)*DCOL);

  for (int it = 0; it < niter; ++it) {
    __syncthreads();                     // prev mfma done reading LDS
    // convert + store staged tile
#pragma unroll
    for (int p = 0; p < 4; ++p) {
      const float v[4] = { ra[p].x, ra[p].y, ra[p].z, ra[p].w };
      short h[4], l[4];
#pragma unroll
      for (int j = 0; j < 4; ++j) {
        h[j] = f2bf_s(v[j]);
        l[j] = f2bf_s(v[j] - bf2f_s(h[j]));
      }
      *(short4*)&Ah[skg][srow + p*64][sko] = make_short4(h[0],h[1],h[2],h[3]);
      *(short4*)&Al[skg][srow + p*64][sko] = make_short4(l[0],l[1],l[2],l[3]);
    }
#pragma unroll
    for (int p = 0; p < 2; ++p) {
      const float v[4] = { rw[p].x, rw[p].y, rw[p].z, rw[p].w };
      short h[4], l[4];
#pragma unroll
      for (int j = 0; j < 4; ++j) {
        h[j] = f2bf_s(v[j]);
        l[j] = f2bf_s(v[j] - bf2f_s(h[j]));
      }
      *(short4*)&Wh[skg][srow + p*64][sko] = make_short4(h[0],h[1],h[2],h[3]);
      *(short4*)&Wl[skg][srow + p*64][sko] = make_short4(l[0],l[1],l[2],l[3]);
    }
    __syncthreads();
    if (it + 1 < niter) {                // prefetch next K-step during mfma
#pragma unroll
      for (int p = 0; p < 4; ++p)
        ra[p] = *(const float4*)(Ap + (it+1)*BKK + (size_t)(p*64)*DCOL);
#pragma unroll
      for (int p = 0; p < 2; ++p)
        rw[p] = *(const float4*)(Wp + (it+1)*BKK + (size_t)(p*64)*DCOL);
    }

    // fragment loads
    const int frow = lane & 15;
    const int fkg  = lane >> 4;
    bf16x8 wfh[8], wfl[8];
#pragma unroll
    for (int nt = 0; nt < 8; ++nt) {
      wfh[nt] = *(const bf16x8*)&Wh[fkg][nt*16 + frow][0];
      wfl[nt] = *(const bf16x8*)&Wl[fkg][nt*16 + frow][0];
    }
    bf16x8 afh[2], afl[2];
#pragma unroll
    for (int mt = 0; mt < 2; ++mt) {
      afh[mt] = *(const bf16x8*)&Ah[fkg][wid*32 + mt*16 + frow][0];
      afl[mt] = *(const bf16x8*)&Al[fkg][wid*32 + mt*16 + frow][0];
    }
#pragma unroll
    for (int mt = 0; mt < 2; ++mt)
#pragma unroll
      for (int nt = 0; nt < 8; ++nt) {
        acc[mt][nt] = __builtin_amdgcn_mfma_f32_16x16x32_bf16(
            afh[mt], wfh[nt], acc[mt][nt], 0, 0, 0);
        acc[mt][nt] = __builtin_amdgcn_mfma_f32_16x16x32_bf16(
            afh[mt], wfl[nt], acc[mt][nt], 0, 0, 0);
        acc[mt][nt] = __builtin_amdgcn_mfma_f32_16x16x32_bf16(
            afl[mt], wfh[nt], acc[mt][nt], 0, 0, 0);
      }
  }

  // epilogue: write fp32 partials
  float* pp = part + (size_t)sk * (BATCH * PNUM);
#pragma unroll
  for (int mt = 0; mt < 2; ++mt)
#pragma unroll
    for (int nt = 0; nt < 8; ++nt) {
      const int col = bn*128 + nt*16 + (lane & 15);
#pragma unroll
      for (int r = 0; r < 4; ++r) {
        const int row = wid*32 + mt*16 + (lane >> 4)*4 + r;
        pp[(size_t)row * PNUM + col] = acc[mt][nt][r];
      }
    }
}

// ---------------------------------------------------------------------------
// K3: out[b][p] = sigmoid(sum_sl pstr[sl][p] + sum_s partial[s][b][p])
// ---------------------------------------------------------------------------
__global__ __launch_bounds__(256) void k3_combine(
    const float* __restrict__ part, const float* __restrict__ pstr,
    float* __restrict__ out, const int spl)
{
  const int g = blockIdx.x * 256 + threadIdx.x;
  const int i4 = g * 4;
  const int p = i4 & (PNUM - 1);
  float acc[4] = {0.f, 0.f, 0.f, 0.f};
#pragma unroll
  for (int sl = 0; sl < SLICES; ++sl) {
    const float4 s4 = *(const float4*)(pstr + sl*PNUM + p);
    acc[0]+=s4.x; acc[1]+=s4.y; acc[2]+=s4.z; acc[3]+=s4.w;
  }
  for (int s = 0; s < spl; ++s) {
    const float4 v = *(const float4*)(part + (size_t)s * (BATCH*PNUM) + i4);
    acc[0]+=v.x; acc[1]+=v.y; acc[2]+=v.z; acc[3]+=v.w;
  }
  float4 o;
  o.x = 1.f / (1.f + __expf(-acc[0]));
  o.y = 1.f / (1.f + __expf(-acc[1]));
  o.z = 1.f / (1.f + __expf(-acc[2]));
  o.w = 1.f / (1.f + __expf(-acc[3]));
  *(float4*)(out + i4) = o;
}

extern "C" void kernel_launch(void* const* d_in, const int* in_sizes, int n_in,
                              void* d_out, int out_size, void* d_ws, size_t ws_size,
                              hipStream_t stream)
{
  const float* spikes = (const float*)d_in[0];   // (256, 8192)
  const float* hist   = (const float*)d_in[1];   // (101, 8192)
  const float* templ  = (const float*)d_in[2];   // (1024, 10, 8192)
  const float* wts    = (const float*)d_in[3];   // (1024, 8192)
  const float* ck     = (const float*)d_in[4];   // (5, 10)
  const int*   hidx   = (const int*)d_in[5];     // scalar
  float* ws  = (float*)d_ws;
  float* out = (float*)d_out;

  int spl = 32;                                   // split-K factor
  while (spl > 1 &&
         ws_size < ((size_t)WS_PART + (size_t)spl * BATCH * PNUM) * 4)
    spl >>= 1;
  const int ksub = DCOL / spl;                    // 256 at spl=32

  k0_prep<<<dim3(8), dim3(256), 0, stream>>>(spikes, hist, ck, hidx, ws);
  k1_strength<<<dim3(SLICES, PNUM), dim3(256), 0, stream>>>(
      templ, ws + WS_K2, ws + WS_RECENT, ws + WS_RINV, ws + WS_PSTR);
  k2_mfma<<<dim3(spl, PNUM/128), dim3(512), 0, stream>>>(
      spikes, wts, ws + WS_PART, ksub);
  k3_combine<<<dim3(BATCH*PNUM/(256*4)), dim3(256), 0, stream>>>(
      ws + WS_PART, ws + WS_PSTR, out, spl);
}

// Round 9
// 104.023 us; speedup vs baseline: 3.2360x; 1.0126x over previous
//
#include <hip/hip_runtime.h>
#include <math.h>

#define DCOL 8192
#define PNUM 1024
#define BATCH 256
#define HISTLEN 101
#define WIN 10
#define NK 5
#define EPSF 1e-6f
#define SLICES 8
#define SLICE_COLS (DCOL/SLICES)        // 1024
#define PPB 4                           // patterns per k1 block
#define BKK 32                          // k2 K-step

// ws layout (float offsets)
#define WS_RECENT 0                         // 10*8192            -> 81920
#define WS_RINV   (WIN*DCOL)                // 81920, 5*8192      -> 122880
#define WS_PSTR   (WS_RINV + NK*DCOL)       // 122880, 8*1024     -> 131072
#define WS_K2     (WS_PSTR + SLICES*PNUM)   // 131072, 50 floats
#define WS_PART   131584                    // split-K partials, spl*256*1024

typedef __attribute__((ext_vector_type(8))) short bf16x8;   // 8 bf16 = 4 VGPR
typedef __attribute__((ext_vector_type(4))) float f32x4;

__device__ inline short f2bf_s(float x) {               // RNE fp32->bf16 bits
  union { float f; unsigned u; } c; c.f = x;
  unsigned r = c.u + 0x7FFFu + ((c.u >> 16) & 1u);
  return (short)(r >> 16);
}
__device__ inline float bf2f_s(short b) {
  union { unsigned u; float f; } c; c.u = ((unsigned)(unsigned short)b) << 16;
  return c.f;
}

// ---------------------------------------------------------------------------
// K0: build `recent` (last 10 history rows with row hist_idx replaced by
// input_spikes[0]), rinv[k][d] = 1/(sqrt(sum_w K2[k][w]*recent^2)+eps),
// and the squared-kernel table k2 -> ws.
// ---------------------------------------------------------------------------
__global__ __launch_bounds__(256) void k0_prep(
    const float* __restrict__ spikes, const float* __restrict__ hist,
    const float* __restrict__ ck, const int* __restrict__ hidxp,
    float* __restrict__ ws)
{
  const int g = blockIdx.x * 256 + threadIdx.x;   // 0..2047
  const int col = g * 4;
  int hidx = hidxp[0] % HISTLEN;
  if (hidx < 0) hidx += HISTLEN;

  if (blockIdx.x == 0 && threadIdx.x < NK*WIN) {
    const float v = ck[threadIdx.x];
    ws[WS_K2 + threadIdx.x] = v * v;
  }

  float k2[NK][WIN];
#pragma unroll
  for (int k = 0; k < NK; ++k)
#pragma unroll
    for (int w = 0; w < WIN; ++w) { float v = ck[k*WIN + w]; k2[k][w] = v * v; }

  float rn[NK][4];
#pragma unroll
  for (int k = 0; k < NK; ++k)
#pragma unroll
    for (int j = 0; j < 4; ++j) rn[k][j] = 0.f;

#pragma unroll
  for (int w = 0; w < WIN; ++w) {
    const int row = HISTLEN - WIN + w;            // 91..100
    const float* src = (row == hidx) ? spikes : (hist + (size_t)row * DCOL);
    const float4 r = *(const float4*)(src + col);
    *(float4*)(ws + WS_RECENT + w*DCOL + col) = r;
    const float rr[4] = { r.x, r.y, r.z, r.w };
#pragma unroll
    for (int k = 0; k < NK; ++k)
#pragma unroll
      for (int j = 0; j < 4; ++j) rn[k][j] += k2[k][w] * rr[j] * rr[j];
  }

#pragma unroll
  for (int k = 0; k < NK; ++k) {
    float o[4];
#pragma unroll
    for (int j = 0; j < 4; ++j) o[j] = 1.0f / (sqrtf(rn[k][j]) + EPSF);
    float4 v; v.x = o[0]; v.y = o[1]; v.z = o[2]; v.w = o[3];
    *(float4*)(ws + WS_RINV + k*DCOL + col) = v;
  }
}

// ---------------------------------------------------------------------------
// K1: persistent blocks. grid = (8 slices, 256 pattern-groups); each block
// owns one 1024-col slice of 4 CONSECUTIVE patterns (templates of
// consecutive patterns are contiguous -> one flat 40-row stream).
//  - recent (40 VGPR) + rinv (20 VGPR) loaded once per block
//  - 6-deep template ring refills ACROSS pattern boundaries: the HBM
//    stream never drains; prologue/drain paid once per 4 patterns
//  - NO per-pattern __syncthreads (compiler's barrier vmcnt(0) would drain
//    the ring): per-wave partials -> red[pi][wid], one barrier at end.
// ---------------------------------------------------------------------------
__global__ __launch_bounds__(256) void k1_strength(
    const float* __restrict__ templ, const float* __restrict__ wk2,
    const float* __restrict__ recent, const float* __restrict__ rinv,
    float* __restrict__ pstr)
{
  __shared__ float red[PPB][4];
  const int sl  = blockIdx.x;
  const int p0  = blockIdx.y * PPB;
  const int tid = threadIdx.x;
  const int wid = tid >> 6;
  const int col = tid * 4;

  const float* __restrict__ tbase  = templ + (size_t)p0 * WIN * DCOL + sl*SLICE_COLS + col;
  const float* __restrict__ rbase  = recent + sl*SLICE_COLS + col;
  const float* __restrict__ ribase = rinv   + sl*SLICE_COLS + col;

  // once-per-block loads (L2-resident)
  float4 r[WIN];
#pragma unroll
  for (int w = 0; w < WIN; ++w)
    r[w] = *(const float4*)(rbase + w*DCOL);
  float4 ri[NK];
#pragma unroll
  for (int k = 0; k < NK; ++k)
    ri[k] = *(const float4*)(ribase + k*DCOL);

  // 6-deep ring over the flat 40-row template stream
  float4 tp[6];
#pragma unroll
  for (int i = 0; i < 6; ++i)
    tp[i] = *(const float4*)(tbase + (size_t)i*DCOL);

#pragma unroll
  for (int pi = 0; pi < PPB; ++pi) {
    float nj[NK][4], tj[NK][4];
#pragma unroll
    for (int k = 0; k < NK; ++k)
#pragma unroll
      for (int j = 0; j < 4; ++j) { nj[k][j] = 0.f; tj[k][j] = 0.f; }

#pragma unroll
    for (int w = 0; w < WIN; ++w) {
      const int t = pi*WIN + w;
      const float4 t4 = tp[t % 6];
      if (t + 6 < PPB*WIN)                         // refill 6 rows ahead
        tp[t % 6] = *(const float4*)(tbase + (size_t)(t + 6)*DCOL);
      const float4 r4 = r[w];
      const float x[4] = { r4.x*t4.x, r4.y*t4.y, r4.z*t4.z, r4.w*t4.w };
      const float y[4] = { t4.x*t4.x, t4.y*t4.y, t4.z*t4.z, t4.w*t4.w };
#pragma unroll
      for (int k = 0; k < NK; ++k) {
        const float cf = wk2[k*WIN + w];           // uniform -> s_load
#pragma unroll
        for (int j = 0; j < 4; ++j) {
          nj[k][j] = fmaf(cf, x[j], nj[k][j]);
          tj[k][j] = fmaf(cf, y[j], tj[k][j]);
        }
      }
    }

    float acc[4] = {0.f, 0.f, 0.f, 0.f};
#pragma unroll
    for (int k = 0; k < NK; ++k) {
      const float rik[4] = { ri[k].x, ri[k].y, ri[k].z, ri[k].w };
#pragma unroll
      for (int j = 0; j < 4; ++j)
        acc[j] += nj[k][j] * rik[j] * rsqrtf(tj[k][j]);
    }
    float a = acc[0] + acc[1] + acc[2] + acc[3];
#pragma unroll
    for (int off = 32; off > 0; off >>= 1) a += __shfl_down(a, off, 64);
    if ((tid & 63) == 0) red[pi][wid] = a;         // no barrier here
  }

  __syncthreads();                                 // single end-of-block barrier
  if (tid < PPB) {
    const float s = red[tid][0] + red[tid][1] + red[tid][2] + red[tid][3];
    pstr[sl*PNUM + p0 + tid] = s * (1.0f / (NK * DCOL));
  }
}

// ---------------------------------------------------------------------------
// K2: split-bf16 MFMA GEMM. C = A_hi*W_hi + A_hi*W_lo + A_lo*W_hi (lo*lo
// dropped, ~2^-18 rel). BM=256, BN=128, BK=32, 512 threads, spl split-K.
// grid = (spl, 8) = 256 blocks = exactly 1/CU at spl=32. (unchanged)
// ---------------------------------------------------------------------------
__global__ __launch_bounds__(512) void k2_mfma(
    const float* __restrict__ A, const float* __restrict__ Wt,
    float* __restrict__ part, const int ksub)
{
  __shared__ short Ah[4][256][8], Al[4][256][8];   // 16 KB each
  __shared__ short Wh[4][128][8], Wl[4][128][8];   // 8 KB each -> 48 KB total

  const int sk  = blockIdx.x;
  const int bn  = blockIdx.y;
  const int tid = threadIdx.x;          // 0..511
  const int lane = tid & 63;
  const int wid  = tid >> 6;            // 0..7
  const size_t k0 = (size_t)sk * ksub;

  const int srow = tid >> 3;            // 0..63
  const int skc  = (tid & 7) * 4;       // k offset 0..28
  const int skg  = skc >> 3;            // kgrp
  const int sko  = skc & 7;             // 0 or 4

  const float* Ap = A  + (size_t)srow * DCOL + k0 + skc;
  const float* Wp = Wt + (size_t)(bn*128 + srow) * DCOL + k0 + skc;

  f32x4 acc[2][8];
#pragma unroll
  for (int mt = 0; mt < 2; ++mt)
#pragma unroll
    for (int nt = 0; nt < 8; ++nt)
#pragma unroll
      for (int r = 0; r < 4; ++r) acc[mt][nt][r] = 0.f;

  const int niter = ksub / BKK;
  float4 ra[4], rw[2];
#pragma unroll
  for (int p = 0; p < 4; ++p) ra[p] = *(const float4*)(Ap + (size_t)(p*64)*DCOL);
#pragma unroll
  for (int p = 0; p < 2; ++p) rw[p] = *(const float4*)(Wp + (size_t)(p*64)*DCOL);

  for (int it = 0; it < niter; ++it) {
    __syncthreads();                     // prev mfma done reading LDS
#pragma unroll
    for (int p = 0; p < 4; ++p) {
      const float v[4] = { ra[p].x, ra[p].y, ra[p].z, ra[p].w };
      short h[4], l[4];
#pragma unroll
      for (int j = 0; j < 4; ++j) {
        h[j] = f2bf_s(v[j]);
        l[j] = f2bf_s(v[j] - bf2f_s(h[j]));
      }
      *(short4*)&Ah[skg][srow + p*64][sko] = make_short4(h[0],h[1],h[2],h[3]);
      *(short4*)&Al[skg][srow + p*64][sko] = make_short4(l[0],l[1],l[2],l[3]);
    }
#pragma unroll
    for (int p = 0; p < 2; ++p) {
      const float v[4] = { rw[p].x, rw[p].y, rw[p].z, rw[p].w };
      short h[4], l[4];
#pragma unroll
      for (int j = 0; j < 4; ++j) {
        h[j] = f2bf_s(v[j]);
        l[j] = f2bf_s(v[j] - bf2f_s(h[j]));
      }
      *(short4*)&Wh[skg][srow + p*64][sko] = make_short4(h[0],h[1],h[2],h[3]);
      *(short4*)&Wl[skg][srow + p*64][sko] = make_short4(l[0],l[1],l[2],l[3]);
    }
    __syncthreads();
    if (it + 1 < niter) {                // prefetch next K-step during mfma
#pragma unroll
      for (int p = 0; p < 4; ++p)
        ra[p] = *(const float4*)(Ap + (it+1)*BKK + (size_t)(p*64)*DCOL);
#pragma unroll
      for (int p = 0; p < 2; ++p)
        rw[p] = *(const float4*)(Wp + (it+1)*BKK + (size_t)(p*64)*DCOL);
    }

    const int frow = lane & 15;
    const int fkg  = lane >> 4;
    bf16x8 wfh[8], wfl[8];
#pragma unroll
    for (int nt = 0; nt < 8; ++nt) {
      wfh[nt] = *(const bf16x8*)&Wh[fkg][nt*16 + frow][0];
      wfl[nt] = *(const bf16x8*)&Wl[fkg][nt*16 + frow][0];
    }
    bf16x8 afh[2], afl[2];
#pragma unroll
    for (int mt = 0; mt < 2; ++mt) {
      afh[mt] = *(const bf16x8*)&Ah[fkg][wid*32 + mt*16 + frow][0];
      afl[mt] = *(const bf16x8*)&Al[fkg][wid*32 + mt*16 + frow][0];
    }
#pragma unroll
    for (int mt = 0; mt < 2; ++mt)
#pragma unroll
      for (int nt = 0; nt < 8; ++nt) {
        acc[mt][nt] = __builtin_amdgcn_mfma_f32_16x16x32_bf16(
            afh[mt], wfh[nt], acc[mt][nt], 0, 0, 0);
        acc[mt][nt] = __builtin_amdgcn_mfma_f32_16x16x32_bf16(
            afh[mt], wfl[nt], acc[mt][nt], 0, 0, 0);
        acc[mt][nt] = __builtin_amdgcn_mfma_f32_16x16x32_bf16(
            afl[mt], wfh[nt], acc[mt][nt], 0, 0, 0);
      }
  }

  float* pp = part + (size_t)sk * (BATCH * PNUM);
#pragma unroll
  for (int mt = 0; mt < 2; ++mt)
#pragma unroll
    for (int nt = 0; nt < 8; ++nt) {
      const int col = bn*128 + nt*16 + (lane & 15);
#pragma unroll
      for (int r = 0; r < 4; ++r) {
        const int row = wid*32 + mt*16 + (lane >> 4)*4 + r;
        pp[(size_t)row * PNUM + col] = acc[mt][nt][r];
      }
    }
}

// ---------------------------------------------------------------------------
// K3: out[b][p] = sigmoid(sum_sl pstr[sl][p] + sum_s partial[s][b][p])
// ---------------------------------------------------------------------------
__global__ __launch_bounds__(256) void k3_combine(
    const float* __restrict__ part, const float* __restrict__ pstr,
    float* __restrict__ out, const int spl)
{
  const int g = blockIdx.x * 256 + threadIdx.x;
  const int i4 = g * 4;
  const int p = i4 & (PNUM - 1);
  float acc[4] = {0.f, 0.f, 0.f, 0.f};
#pragma unroll
  for (int sl = 0; sl < SLICES; ++sl) {
    const float4 s4 = *(const float4*)(pstr + sl*PNUM + p);
    acc[0]+=s4.x; acc[1]+=s4.y; acc[2]+=s4.z; acc[3]+=s4.w;
  }
  for (int s = 0; s < spl; ++s) {
    const float4 v = *(const float4*)(part + (size_t)s * (BATCH*PNUM) + i4);
    acc[0]+=v.x; acc[1]+=v.y; acc[2]+=v.z; acc[3]+=v.w;
  }
  float4 o;
  o.x = 1.f / (1.f + __expf(-acc[0]));
  o.y = 1.f / (1.f + __expf(-acc[1]));
  o.z = 1.f / (1.f + __expf(-acc[2]));
  o.w = 1.f / (1.f + __expf(-acc[3]));
  *(float4*)(out + i4) = o;
}

extern "C" void kernel_launch(void* const* d_in, const int* in_sizes, int n_in,
                              void* d_out, int out_size, void* d_ws, size_t ws_size,
                              hipStream_t stream)
{
  const float* spikes = (const float*)d_in[0];   // (256, 8192)
  const float* hist   = (const float*)d_in[1];   // (101, 8192)
  const float* templ  = (const float*)d_in[2];   // (1024, 10, 8192)
  const float* wts    = (const float*)d_in[3];   // (1024, 8192)
  const float* ck     = (const float*)d_in[4];   // (5, 10)
  const int*   hidx   = (const int*)d_in[5];     // scalar
  float* ws  = (float*)d_ws;
  float* out = (float*)d_out;

  int spl = 32;                                   // split-K factor
  while (spl > 1 &&
         ws_size < ((size_t)WS_PART + (size_t)spl * BATCH * PNUM) * 4)
    spl >>= 1;
  const int ksub = DCOL / spl;                    // 256 at spl=32

  k0_prep<<<dim3(8), dim3(256), 0, stream>>>(spikes, hist, ck, hidx, ws);
  k1_strength<<<dim3(SLICES, PNUM/PPB), dim3(256), 0, stream>>>(
      templ, ws + WS_K2, ws + WS_RECENT, ws + WS_RINV, ws + WS_PSTR);
  k2_mfma<<<dim3(spl, PNUM/128), dim3(512), 0, stream>>>(
      spikes, wts, ws + WS_PART, ksub);
  k3_combine<<<dim3(BATCH*PNUM/(256*4)), dim3(256), 0, stream>>>(
      ws + WS_PART, ws + WS_PSTR, out, spl);
}